// Round 5
// baseline (277279.785 us; speedup 1.0000x reference)
//
#include <hip/hip_runtime.h>

// FoldedAutoencoder — round 7: batch-parallel GEMM, hardened.
// Architecture (unchanged from R4): 64 blocks x 1024 threads; block i owns
// 8 hidden rows j for ALL 64 batches (lane = batch). Per-step weight slice =
// 147 KB/block, private -> L2-resident; h-state [2][512][64] f32 ping-pong in
// ws via agent-scope atomics; 2 flag barriers/step (store + load-only poll,
// the protocol that passed correctness in R3).
// Hardening vs R4 (container died, no counters):
//  - P2 sequenced: one 32-VGPR prefetch at a time (was 64).
//  - bounded spins (~1.5 s) -> wrong answer + counters instead of a hang.
//  - PAN fallback machinery deleted (ws >= ~10 MB proven in R2/R3).
//  - embeddings precomputed into ws (no sincosf in the serial loop).

typedef unsigned short u16;
typedef unsigned int u32;
typedef unsigned long long u64;

__device__ __forceinline__ float b2f(u16 u) { return __uint_as_float(((u32)u) << 16); }
__device__ __forceinline__ float blo(u32 u) { return __uint_as_float(u << 16); }
__device__ __forceinline__ float bhi(u32 u) { return __uint_as_float(u & 0xffff0000u); }
__device__ __forceinline__ u16 f2b(float f) {
    u32 x = __float_as_uint(f);
    u32 r = x + 0x7fffu + ((x >> 16) & 1u);   // RNE
    return (u16)(r >> 16);
}
__device__ __forceinline__ u64 pk(float lo, float hi) {
    return ((u64)__float_as_uint(hi) << 32) | (u64)__float_as_uint(lo);
}

#define SS 512
#define TWO_PI 6.28318530717958647692f
#define BIGF 3.402823466e+38f
#define NBK 64

// ---- workspace layout (all paths f32 in ws) ----
#define BARF_OFF 0                            // 64 ints (memset to 0 each launch)
#define NVG_OFF  4096                         // 64 f32
#define EMB_OFF  8192                         // [512][33][64] f32 = 4,325,376 B
#define VS2_OFF  (EMB_OFF + 4325376)          // [512][64] f32 = 131,072 B
#define H0G_OFF  (VS2_OFF + 131072)           // [2][512][64] f32 = 262,144 B
#define H1G_OFF  (H0G_OFF + 262144)           // 262,144 B
#define CTX_OFF  (H1G_OFF + 262144)           // [512][64] f32 = 131,072 B
#define NEED_NEW ((unsigned long long)(CTX_OFF + 131072))   // 5,120,000 B

struct P {
    const void* lc;     // (B,3,S)
    const void* freq;   // (B,)
    const void* W[12];  // Wih0,bih0,Whh0,bhh0,Wih1,bih1,Whh1,bhh1,Wl1,bl1,Wl2,bl2
    void* out;          // (B,16)
    void* ws;
    unsigned long long ws_size;
};

__device__ __forceinline__ bool inputs_are_bf16(const void* freq) {
    const u16* q = (const u16*)freq;
    bool ok = true;
    for (int i = 0; i < 64; ++i) {
        float v = b2f(q[i]);
        ok = ok && (v >= 0.4f) && (v <= 5.5f);
    }
    return ok;
}

template<bool BF>
__device__ __forceinline__ float ldw(const void* p, size_t i) {
    if constexpr (BF) return b2f(((const u16*)p)[i]);
    else              return ((const float*)p)[i];
}

// agent-scope helpers
__device__ __forceinline__ void sc_store_f(float* ptr, float v) {
    __hip_atomic_store(ptr, v, __ATOMIC_RELAXED, __HIP_MEMORY_SCOPE_AGENT);
}
__device__ __forceinline__ float sc_load_f(const float* ptr) {
    return __hip_atomic_load(ptr, __ATOMIC_RELAXED, __HIP_MEMORY_SCOPE_AGENT);
}
__device__ __forceinline__ void sc_store_u64(u64* ptr, u64 v) {
    __hip_atomic_store(ptr, v, __ATOMIC_RELAXED, __HIP_MEMORY_SCOPE_AGENT);
}
__device__ __forceinline__ u64 sc_load_u64(const u64* ptr) {
    return __hip_atomic_load(ptr, __ATOMIC_RELAXED, __HIP_MEMORY_SCOPE_AGENT);
}
__device__ __forceinline__ void sc_store_i(int* ptr, int v) {
    __hip_atomic_store(ptr, v, __ATOMIC_RELAXED, __HIP_MEMORY_SCOPE_AGENT);
}
__device__ __forceinline__ int sc_load_i(const int* ptr) {
    return __hip_atomic_load(ptr, __ATOMIC_RELAXED, __HIP_MEMORY_SCOPE_AGENT);
}

// ======================= shared preproc building blocks =======================
struct PreShm {
    float ph[512], mg[512], skey[512], sig[512], vld[512];
    int   sidx[512];
    float ps2[512], ms2[512], vs2[512];
    float pn[50][8], pd[50][8], smoothv[50];
    float gshift, nv;
};

__device__ void bitonic512a(float* skey, int* sidx, int tid, bool act) {
    for (int k = 2; k <= 512; k <<= 1) {
        for (int j = k >> 1; j > 0; j >>= 1) {
            int ixj = tid ^ j;
            if (act && ixj > tid) {
                float ka = skey[tid], kb = skey[ixj];
                int ia = sidx[tid], ib = sidx[ixj];
                bool up = ((tid & k) == 0);
                bool agtb = (ka > kb) || (ka == kb && ia > ib);
                if (agtb == up) {
                    skey[tid] = kb; skey[ixj] = ka;
                    sidx[tid] = ib; sidx[ixj] = ia;
                }
            }
            __syncthreads();
        }
    }
}

template<bool BF>
__device__ void preproc_core(const P& p, PreShm& s, int b, int tid, int nthr) {
    bool act = tid < 512;
    if (act) {
        float period = 2.0f / ldw<BF>(p.freq, b);
        float t = ldw<BF>(p.lc, (size_t)b * 3 * SS + tid);
        float m = ldw<BF>(p.lc, (size_t)b * 3 * SS + SS + tid);
        float ph0 = fmodf(t, period) / period;
        s.ph[tid] = ph0; s.mg[tid] = m;
        s.skey[tid] = ph0; s.sidx[tid] = tid;
    }
    __syncthreads();
    bitonic512a(s.skey, s.sidx, tid, act);
    if (act) {
        float pc = s.skey[tid];
        float wv[4], mv[4];
        float wsum = 0.f, wm = 0.f;
        const int offs[4] = {-2, -1, 1, 2};
#pragma unroll
        for (int c = 0; c < 4; ++c) {
            int jj = (tid + offs[c]) & 511;
            float d = s.skey[jj] - pc;
            float u = d - 0.5f; u = u - floorf(u);
            float dphi = u - 0.5f;
            float w = 0.75f * (1.0f - dphi * dphi);
            float mm = s.mg[s.sidx[jj]];
            wv[c] = w; mv[c] = mm;
            wsum += w; wm += w * mm;
        }
        float loc = wm / wsum;
        float s2 = 0.f;
#pragma unroll
        for (int c = 0; c < 4; ++c) { float dm = mv[c] - loc; s2 += dm * dm * wv[c]; }
        float scale = sqrtf(s2 / (wsum - 1.0f));
        s.sig[s.sidx[tid]] = loc + 5.0f * scale;
    }
    __syncthreads();
    if (act) s.vld[tid] = (s.mg[tid] > s.sig[tid]) ? 0.0f : 1.0f;
    __syncthreads();
    if (tid == 0) {
        float acc = 0.f;
        for (int i = 0; i < 512; ++i) acc += s.vld[i];
        s.nv = acc;
    }
    {
        int g = tid >> 3, pq = tid & 7;
        if (g < 50) {
            float gv = (float)g * (1.0f / 49.0f);
            float num = 0.f, den = 0.f;
            int s0 = pq * 64;
            for (int ss = s0; ss < s0 + 64; ++ss) {
                float d = gv - s.ph[ss];
                float c = cosf(TWO_PI * d);
                float K = expf((c - 1.0f) * 100.0f);
                float w = s.vld[ss] * K;
                den += w; num += w * s.mg[ss];
            }
            s.pn[g][pq] = num; s.pd[g][pq] = den;
        }
    }
    __syncthreads();
    if (tid < 50) {
        float num = 0.f, den = 0.f;
#pragma unroll
        for (int c = 0; c < 8; ++c) { num += s.pn[tid][c]; den += s.pd[tid][c]; }
        s.smoothv[tid] = num / den;
    }
    __syncthreads();
    if (tid == 0) {
        float best = s.smoothv[0]; int bi = 0;
        for (int g = 1; g < 50; ++g) if (s.smoothv[g] > best) { best = s.smoothv[g]; bi = g; }
        s.gshift = (float)bi * (1.0f / 49.0f);
    }
    __syncthreads();
    if (act) {
        float p2 = s.ph[tid] - s.gshift;
        s.ph[tid] = p2;
        s.skey[tid] = (s.vld[tid] > 0.f) ? p2 : BIGF;
        s.sidx[tid] = tid;
    }
    __syncthreads();
    bitonic512a(s.skey, s.sidx, tid, act);
    if (act) {
        int o = s.sidx[tid];
        s.ps2[tid] = s.ph[o]; s.ms2[tid] = s.mg[o]; s.vs2[tid] = s.vld[o];
    }
    __syncthreads();
    (void)nthr;
}

// ======================= fallback kernel (R0-verified, 64x512) =======================
struct ShmOld {
    PreShm pre;
    float h0[512], h1[512];
    float eL[33];
};

template<bool BF>
__device__ void run_old(const P& p, ShmOld& s) {
    int b = blockIdx.x, tid = threadIdx.x;
    preproc_core<BF>(p, s.pre, b, tid, 512);

    int j = tid;
    float wr0[33], wz0[33], wn0[33];
#pragma unroll
    for (int d = 0; d < 33; ++d) {
        wr0[d] = ldw<BF>(p.W[0], (size_t)j * 33 + d);
        wz0[d] = ldw<BF>(p.W[0], ((size_t)j + 512) * 33 + d);
        wn0[d] = ldw<BF>(p.W[0], ((size_t)j + 1024) * 33 + d);
    }
    float bi0r = ldw<BF>(p.W[1], j), bi0z = ldw<BF>(p.W[1], j + 512), bi0n = ldw<BF>(p.W[1], j + 1024);
    float bh0r = ldw<BF>(p.W[3], j), bh0z = ldw<BF>(p.W[3], j + 512), bh0n = ldw<BF>(p.W[3], j + 1024);
    float bi1r = ldw<BF>(p.W[5], j), bi1z = ldw<BF>(p.W[5], j + 512), bi1n = ldw<BF>(p.W[5], j + 1024);
    float bh1r = ldw<BF>(p.W[7], j), bh1z = ldw<BF>(p.W[7], j + 512), bh1n = ldw<BF>(p.W[7], j + 1024);

    s.h0[j] = 0.f; s.h1[j] = 0.f;
    float cacc = 0.f;
    __syncthreads();

    for (int tt = 0; tt < 512; ++tt) {
        if (j < 16) {
            float ang = TWO_PI * s.pre.ps2[tt] * (float)(j + 1);
            float sv, cv; sincosf(ang, &sv, &cv);
            s.eL[j] = cv; s.eL[16 + j] = sv;
        }
        if (j == 32) s.eL[32] = s.pre.ms2[tt];
        __syncthreads();
        float xr = bi0r, xz = bi0z, xn = bi0n;
#pragma unroll
        for (int d = 0; d < 33; ++d) {
            float e = s.eL[d];
            xr += wr0[d] * e; xz += wz0[d] * e; xn += wn0[d] * e;
        }
        float ar = bh0r, az = bh0z, an = bh0n;
        for (int k = 0; k < 512; ++k) {
            float h = s.h0[k];
            ar += ldw<BF>(p.W[2], (size_t)j * 512 + k) * h;
            az += ldw<BF>(p.W[2], ((size_t)j + 512) * 512 + k) * h;
            an += ldw<BF>(p.W[2], ((size_t)j + 1024) * 512 + k) * h;
        }
        float h0prev = s.h0[j];
        float r0 = 1.0f / (1.0f + expf(-(xr + ar)));
        float z0 = 1.0f / (1.0f + expf(-(xz + az)));
        float n0 = tanhf(xn + r0 * an);
        float nh0 = (1.0f - z0) * n0 + z0 * h0prev;
        __syncthreads();
        s.h0[j] = nh0;
        __syncthreads();
        float yr = bi1r, yz = bi1z, yn = bi1n;
        float cr = bh1r, cz = bh1z, cn = bh1n;
        for (int k = 0; k < 512; ++k) {
            float h = s.h0[k], g = s.h1[k];
            yr += ldw<BF>(p.W[4], (size_t)j * 512 + k) * h;
            yz += ldw<BF>(p.W[4], ((size_t)j + 512) * 512 + k) * h;
            yn += ldw<BF>(p.W[4], ((size_t)j + 1024) * 512 + k) * h;
            cr += ldw<BF>(p.W[6], (size_t)j * 512 + k) * g;
            cz += ldw<BF>(p.W[6], ((size_t)j + 512) * 512 + k) * g;
            cn += ldw<BF>(p.W[6], ((size_t)j + 1024) * 512 + k) * g;
        }
        float h1prev = s.h1[j];
        float r1 = 1.0f / (1.0f + expf(-(yr + cr)));
        float z1 = 1.0f / (1.0f + expf(-(yz + cz)));
        float n1 = tanhf(yn + r1 * cn);
        float nh1 = (1.0f - z1) * n1 + z1 * h1prev;
        cacc += s.pre.vs2[tt] * nh1;
        __syncthreads();
        s.h1[j] = nh1;
    }
    __syncthreads();

    s.h0[j] = cacc / s.pre.nv;
    __syncthreads();
    float a1 = ldw<BF>(p.W[9], j);
    for (int k = 0; k < 512; ++k) a1 += ldw<BF>(p.W[8], (size_t)j * 512 + k) * s.h0[k];
    float g = 0.5f * a1 * (1.0f + erff(a1 * 0.70710678118654752440f));
    __syncthreads();
    s.h1[j] = g;
    __syncthreads();
    if (j < 16) {
        float a2 = ldw<BF>(p.W[11], j);
        for (int k = 0; k < 512; ++k) a2 += ldw<BF>(p.W[10], (size_t)j * 512 + k) * s.h1[k];
        if constexpr (BF) ((u16*)p.out)[(size_t)b * 16 + j] = f2b(a2);
        else              ((float*)p.out)[(size_t)b * 16 + j] = a2;
    }
}

__global__ __launch_bounds__(512) void fused_kernel_old(P p) {
    __shared__ ShmOld s;
    if (inputs_are_bf16(p.freq)) run_old<true>(p, s);
    else                         run_old<false>(p, s);
}

// ======================= NEW kernel: batch-parallel GEMM, 64x1024 =======================
struct ShmNew {
    union U {
        float hb[2][4096];      // 2 x 16KB h-tiles [64 k][64 b]
        PreShm pre;
    } u;
    float part[8][6][64];       // partial combine + MLP scratch (12KB)
};

// grid barrier: store-own-flag + load-only polling; BOUNDED (escape hatch).
__device__ __forceinline__ void gbar(int* barf, int bid, int ep, int tid) {
    __syncthreads();                 // drains this block's prior VMEM stores
    if (tid == 0) sc_store_i(&barf[bid], ep);
    if (tid < NBK) {
        int it = 0;
        while (sc_load_i(&barf[tid]) < ep) {
            __builtin_amdgcn_s_sleep(8);
            if (++it > 3000000) break;          // ~1.5 s: fail loud, not hung
        }
    }
    __syncthreads();
}

__device__ __forceinline__ void load16(const u64* src, int tid, u64* pv) {
#pragma unroll
    for (int i = 0; i < 16; ++i) pv[i] = sc_load_u64(&src[tid + i * 1024]);
}
__device__ __forceinline__ void wr_tile(float* buf, u64 a, u64 b8, int tid) {
    ((u64*)buf)[tid] = a;
    ((u64*)buf)[tid + 1024] = b8;
}

// 3 gate-row dot partial over one 64-k tile; lane = batch b; weights wave-uniform.
template<bool BF>
__device__ __forceinline__ void dot3_tile(const void* Wbase, int j, int T, int half,
                                          const float* __restrict__ hbT, int b,
                                          float& ar, float& az, float& an) {
    const int k0 = T * 64 + half * 32;
    const int kk0 = half * 32;
    if constexpr (BF) {
        const u16* Wr = (const u16*)Wbase + (size_t)j * 512;
        const u16* Wz = (const u16*)Wbase + ((size_t)j + 512) * 512;
        const u16* Wn = (const u16*)Wbase + ((size_t)j + 1024) * 512;
#pragma unroll
        for (int i = 0; i < 32; i += 8) {
            uint4 wr = *(const uint4*)(Wr + k0 + i);
            uint4 wz = *(const uint4*)(Wz + k0 + i);
            uint4 wn = *(const uint4*)(Wn + k0 + i);
            float h0 = hbT[(kk0 + i + 0) * 64 + b], h1 = hbT[(kk0 + i + 1) * 64 + b];
            float h2 = hbT[(kk0 + i + 2) * 64 + b], h3 = hbT[(kk0 + i + 3) * 64 + b];
            float h4 = hbT[(kk0 + i + 4) * 64 + b], h5 = hbT[(kk0 + i + 5) * 64 + b];
            float h6 = hbT[(kk0 + i + 6) * 64 + b], h7 = hbT[(kk0 + i + 7) * 64 + b];
            ar += blo(wr.x)*h0 + bhi(wr.x)*h1 + blo(wr.y)*h2 + bhi(wr.y)*h3
                + blo(wr.z)*h4 + bhi(wr.z)*h5 + blo(wr.w)*h6 + bhi(wr.w)*h7;
            az += blo(wz.x)*h0 + bhi(wz.x)*h1 + blo(wz.y)*h2 + bhi(wz.y)*h3
                + blo(wz.z)*h4 + bhi(wz.z)*h5 + blo(wz.w)*h6 + bhi(wz.w)*h7;
            an += blo(wn.x)*h0 + bhi(wn.x)*h1 + blo(wn.y)*h2 + bhi(wn.y)*h3
                + blo(wn.z)*h4 + bhi(wn.z)*h5 + blo(wn.w)*h6 + bhi(wn.w)*h7;
        }
    } else {
        const float* Wr = (const float*)Wbase + (size_t)j * 512;
        const float* Wz = (const float*)Wbase + ((size_t)j + 512) * 512;
        const float* Wn = (const float*)Wbase + ((size_t)j + 1024) * 512;
#pragma unroll
        for (int i = 0; i < 32; i += 4) {
            float4 wr = *(const float4*)(Wr + k0 + i);
            float4 wz = *(const float4*)(Wz + k0 + i);
            float4 wn = *(const float4*)(Wn + k0 + i);
            float h0 = hbT[(kk0 + i + 0) * 64 + b], h1 = hbT[(kk0 + i + 1) * 64 + b];
            float h2 = hbT[(kk0 + i + 2) * 64 + b], h3 = hbT[(kk0 + i + 3) * 64 + b];
            ar += wr.x*h0 + wr.y*h1 + wr.z*h2 + wr.w*h3;
            az += wz.x*h0 + wz.y*h1 + wz.z*h2 + wz.w*h3;
            an += wn.x*h0 + wn.y*h1 + wn.z*h2 + wn.w*h3;
        }
    }
}

// one staged pass: prefetch (32 VGPR) -> 8 double-buffered LDS tiles -> dots
template<bool BF>
__device__ __forceinline__ void gemm_pass(const u64* src, const void* Wbase,
                                          int j, int half, int b, int tid,
                                          ShmNew& s, float& ar, float& az, float& an) {
    u64 pv[16];
    load16(src, tid, pv);
    wr_tile(&s.u.hb[0][0], pv[0], pv[1], tid);
    __syncthreads();
#pragma unroll
    for (int T = 0; T < 8; ++T) {
        if (T < 7) wr_tile(&s.u.hb[(T + 1) & 1][0], pv[2 * T + 2], pv[2 * T + 3], tid);
        dot3_tile<BF>(Wbase, j, T, half, &s.u.hb[T & 1][0], b, ar, az, an);
        __syncthreads();
    }
}

template<bool BF>
__device__ void run_new(const P& p, ShmNew& s) {
    const int bid = blockIdx.x;                 // 0..63: batch (preproc) AND j-group
    const int tid = threadIdx.x;                // 0..1023
    const int b   = tid & 63;                   // lane = batch
    const int w   = tid >> 6;                   // wave 0..15
    const int jj  = w & 7;
    const int half = __builtin_amdgcn_readfirstlane(w >> 3);
    const int j   = __builtin_amdgcn_readfirstlane(bid * 8 + jj);

    char*  wsb  = (char*)p.ws;
    int*   barf = (int*)(wsb + BARF_OFF);
    float* nvg  = (float*)(wsb + NVG_OFF);
    float* embg = (float*)(wsb + EMB_OFF);      // [512][33][64]
    float* vs2g = (float*)(wsb + VS2_OFF);      // [512][64]
    u64*   h0q  = (u64*)(wsb + H0G_OFF);        // [2][16384] u64 (= [2][512][64] f32)
    u64*   h1q  = (u64*)(wsb + H1G_OFF);
    float* ctxg = (float*)(wsb + CTX_OFF);      // [512][64]

    // ---- preproc: block bid handles batch bid; publish emb/vs2/nv; zero h(-1) ----
    preproc_core<BF>(p, s.u.pre, bid, tid, 1024);
    for (int pi = tid; pi < 512 * 16; pi += 1024) {
        int t = pi >> 4, kk = pi & 15;
        float ang = TWO_PI * s.u.pre.ps2[t] * (float)(kk + 1);
        float sv, cv; sincosf(ang, &sv, &cv);
        sc_store_f(&embg[((size_t)t * 33 + kk) * 64 + bid], cv);
        sc_store_f(&embg[((size_t)t * 33 + 16 + kk) * 64 + bid], sv);
    }
    for (int t = tid; t < 512; t += 1024) {
        sc_store_f(&embg[((size_t)t * 33 + 32) * 64 + bid], s.u.pre.ms2[t]);
        sc_store_f(&vs2g[t * 64 + bid], s.u.pre.vs2[t]);
    }
    if (tid == 0) sc_store_f(&nvg[bid], s.u.pre.nv);
    if (tid < 256) {                             // zero parity-1 h(-1) slices
        sc_store_u64(&h0q[16384 + bid * 256 + tid], 0ull);
        sc_store_u64(&h1q[16384 + bid * 256 + tid], 0ull);
    }
    gbar(barf, bid, 1, tid);

    // uniform per-j constants
    float bi0r = ldw<BF>(p.W[1], j), bi0z = ldw<BF>(p.W[1], j + 512), bi0n = ldw<BF>(p.W[1], j + 1024);
    float bh0r = ldw<BF>(p.W[3], j), bh0z = ldw<BF>(p.W[3], j + 512), bh0n = ldw<BF>(p.W[3], j + 1024);
    float bi1r = ldw<BF>(p.W[5], j), bi1z = ldw<BF>(p.W[5], j + 512), bi1n = ldw<BF>(p.W[5], j + 1024);
    float bh1r = ldw<BF>(p.W[7], j), bh1z = ldw<BF>(p.W[7], j + 512), bh1n = ldw<BF>(p.W[7], j + 1024);

    float hp0 = 0.f, hp1 = 0.f, cacc = 0.f;

    for (int t = 0; t < 512; ++t) {
        // ================= P1: h0(t) = GRU0(h0(t-1), emb(t)) =================
        float x0r = 0.f, x0z = 0.f, x0n = 0.f;
        if (w < 8) {                     // x-part from precomputed emb (immutable)
            const float* e0 = embg + (size_t)t * 33 * 64 + b;
            x0r = bi0r; x0z = bi0z; x0n = bi0n;
#pragma unroll
            for (int d = 0; d < 33; ++d) {
                float e = e0[d * 64];
                x0r += ldw<BF>(p.W[0], (size_t)j * 33 + d) * e;
                x0z += ldw<BF>(p.W[0], ((size_t)j + 512) * 33 + d) * e;
                x0n += ldw<BF>(p.W[0], ((size_t)j + 1024) * 33 + d) * e;
            }
        }
        float ar = 0.f, az = 0.f, an = 0.f;
        gemm_pass<BF>(&h0q[((t + 1) & 1) * 16384], p.W[2], j, half, b, tid, s, ar, az, an);
        if (w >= 8) { s.part[jj][0][b] = ar; s.part[jj][1][b] = az; s.part[jj][2][b] = an; }
        __syncthreads();
        if (w < 8) {
            ar += s.part[jj][0][b] + bh0r;
            az += s.part[jj][1][b] + bh0z;
            an += s.part[jj][2][b] + bh0n;
            float r0 = 1.f / (1.f + expf(-(x0r + ar)));
            float z0 = 1.f / (1.f + expf(-(x0z + az)));
            float n0 = tanhf(x0n + r0 * an);
            float nh0 = (1.f - z0) * n0 + z0 * hp0;
            hp0 = nh0;
            float o = __shfl_xor(nh0, 1);
            if (!(b & 1)) sc_store_u64(&h0q[(t & 1) * 16384 + j * 32 + (b >> 1)], pk(nh0, o));
        }
        gbar(barf, bid, 2 + 2 * t, tid);

        // ================= P2: h1(t) = GRU1(h1(t-1), h0(t)) =================
        float yr = 0.f, yz = 0.f, yn = 0.f;
        gemm_pass<BF>(&h0q[(t & 1) * 16384], p.W[4], j, half, b, tid, s, yr, yz, yn);
        float cr = 0.f, cz = 0.f, cn = 0.f;
        gemm_pass<BF>(&h1q[((t + 1) & 1) * 16384], p.W[6], j, half, b, tid, s, cr, cz, cn);
        if (w >= 8) {
            s.part[jj][0][b] = yr; s.part[jj][1][b] = yz; s.part[jj][2][b] = yn;
            s.part[jj][3][b] = cr; s.part[jj][4][b] = cz; s.part[jj][5][b] = cn;
        }
        __syncthreads();
        if (w < 8) {
            yr += s.part[jj][0][b] + bi1r;
            yz += s.part[jj][1][b] + bi1z;
            yn += s.part[jj][2][b] + bi1n;
            cr += s.part[jj][3][b] + bh1r;
            cz += s.part[jj][4][b] + bh1z;
            cn += s.part[jj][5][b] + bh1n;
            float r1 = 1.f / (1.f + expf(-(yr + cr)));
            float z1 = 1.f / (1.f + expf(-(yz + cz)));
            float n1 = tanhf(yn + r1 * cn);
            float nh1 = (1.f - z1) * n1 + z1 * hp1;
            hp1 = nh1;
            cacc += vs2g[t * 64 + b] * nh1;
            float o = __shfl_xor(nh1, 1);
            if (!(b & 1)) sc_store_u64(&h1q[(t & 1) * 16384 + j * 32 + (b >> 1)], pk(nh1, o));
        }
        gbar(barf, bid, 3 + 2 * t, tid);
    }

    // ---- ctx publish ----
    if (w < 8) sc_store_f(&ctxg[(size_t)j * 64 + b], cacc / nvg[b]);
    gbar(barf, bid, 1026, tid);

    // ---- MLP head: block bid handles batch bid ----
    float* ctxL = &s.part[0][0][0];   // 512 floats
    float* gL   = ctxL + 512;         // 512 floats
    if (tid < 512) ctxL[tid] = sc_load_f(&ctxg[(size_t)tid * 64 + bid]);
    __syncthreads();
    if (tid < 512) {
        float a1 = ldw<BF>(p.W[9], tid);
        for (int k = 0; k < 512; ++k) a1 += ldw<BF>(p.W[8], (size_t)tid * 512 + k) * ctxL[k];
        gL[tid] = 0.5f * a1 * (1.f + erff(a1 * 0.70710678118654752440f));
    }
    __syncthreads();
    if (tid < 16) {
        float a2 = ldw<BF>(p.W[11], tid);
        for (int k = 0; k < 512; ++k) a2 += ldw<BF>(p.W[10], (size_t)tid * 512 + k) * gL[k];
        if constexpr (BF) ((u16*)p.out)[(size_t)bid * 16 + tid] = f2b(a2);
        else              ((float*)p.out)[(size_t)bid * 16 + tid] = a2;
    }
}

__global__ __launch_bounds__(1024) void fused_kernel_new(P p) {
    __shared__ ShmNew s;
    if (inputs_are_bf16(p.freq)) run_new<true>(p, s);
    else                         run_new<false>(p, s);
}

extern "C" void kernel_launch(void* const* d_in, const int* in_sizes, int n_in,
                              void* d_out, int out_size, void* d_ws, size_t ws_size,
                              hipStream_t stream) {
    P p;
    p.lc = d_in[0];
    p.freq = d_in[2];
    for (int i = 0; i < 12; ++i) p.W[i] = d_in[3 + i];
    p.out = d_out;
    p.ws = d_ws;
    p.ws_size = (unsigned long long)ws_size;
    if (d_ws && ws_size >= (size_t)NEED_NEW) {
        hipMemsetAsync(d_ws, 0, 4096, stream);    // barrier flags
        fused_kernel_new<<<NBK, 1024, 0, stream>>>(p);
    } else {
        fused_kernel_old<<<64, 512, 0, stream>>>(p);
    }
    (void)in_sizes; (void)n_in; (void)out_size;
}

// Round 6
// 271464.624 us; speedup vs baseline: 1.0214x; 1.0214x over previous
//
#include <hip/hip_runtime.h>

// FoldedAutoencoder — round 8: batch-parallel GEMM, spill-fixed.
// R5 post-mortem: algorithm passed (absmax 0) but __launch_bounds__(1024)
// without min-waves let the compiler target 64 VGPRs -> pv[16] prefetch and
// GEMM working set spilled to scratch -> 204 GB HBM writes, 277 ms at 1.2%
// VALU. Fixes:
//  (1) __launch_bounds__(1024, 4): 1 block/CU, 128-VGPR cap, no spill.
//  (2) one grid barrier per step (mid-step P1->P2). The end-of-step barrier
//      was redundant: h1(t) visibility + all WAR hazards for step t+1 are
//      carried by midbar(t+1) (flag store is preceded by the vmcnt(0) drain
//      in __syncthreads; no block passes midbar while another still reads
//      the parity being overwritten). 513 barriers instead of 1026.
//  (3) LDS dead-flag: spin timeout poisons once, later barriers skip.

typedef unsigned short u16;
typedef unsigned int u32;
typedef unsigned long long u64;

__device__ __forceinline__ float b2f(u16 u) { return __uint_as_float(((u32)u) << 16); }
__device__ __forceinline__ float blo(u32 u) { return __uint_as_float(u << 16); }
__device__ __forceinline__ float bhi(u32 u) { return __uint_as_float(u & 0xffff0000u); }
__device__ __forceinline__ u16 f2b(float f) {
    u32 x = __float_as_uint(f);
    u32 r = x + 0x7fffu + ((x >> 16) & 1u);   // RNE
    return (u16)(r >> 16);
}
__device__ __forceinline__ u64 pk(float lo, float hi) {
    return ((u64)__float_as_uint(hi) << 32) | (u64)__float_as_uint(lo);
}

#define SS 512
#define TWO_PI 6.28318530717958647692f
#define BIGF 3.402823466e+38f
#define NBK 64

// ---- workspace layout ----
#define BARF_OFF 0                            // 64 ints (memset to 0 each launch)
#define NVG_OFF  4096                         // 64 f32
#define EMB_OFF  8192                         // [512][33][64] f32 = 4,325,376 B
#define VS2_OFF  (EMB_OFF + 4325376)          // [512][64] f32
#define H0G_OFF  (VS2_OFF + 131072)           // [2][512][64] f32
#define H1G_OFF  (H0G_OFF + 262144)
#define CTX_OFF  (H1G_OFF + 262144)           // [512][64] f32
#define NEED_NEW ((unsigned long long)(CTX_OFF + 131072))

struct P {
    const void* lc;     // (B,3,S)
    const void* freq;   // (B,)
    const void* W[12];  // Wih0,bih0,Whh0,bhh0,Wih1,bih1,Whh1,bhh1,Wl1,bl1,Wl2,bl2
    void* out;          // (B,16)
    void* ws;
    unsigned long long ws_size;
};

__device__ __forceinline__ bool inputs_are_bf16(const void* freq) {
    const u16* q = (const u16*)freq;
    bool ok = true;
    for (int i = 0; i < 64; ++i) {
        float v = b2f(q[i]);
        ok = ok && (v >= 0.4f) && (v <= 5.5f);
    }
    return ok;
}

template<bool BF>
__device__ __forceinline__ float ldw(const void* p, size_t i) {
    if constexpr (BF) return b2f(((const u16*)p)[i]);
    else              return ((const float*)p)[i];
}

// agent-scope helpers
__device__ __forceinline__ void sc_store_f(float* ptr, float v) {
    __hip_atomic_store(ptr, v, __ATOMIC_RELAXED, __HIP_MEMORY_SCOPE_AGENT);
}
__device__ __forceinline__ float sc_load_f(const float* ptr) {
    return __hip_atomic_load(ptr, __ATOMIC_RELAXED, __HIP_MEMORY_SCOPE_AGENT);
}
__device__ __forceinline__ void sc_store_u64(u64* ptr, u64 v) {
    __hip_atomic_store(ptr, v, __ATOMIC_RELAXED, __HIP_MEMORY_SCOPE_AGENT);
}
__device__ __forceinline__ u64 sc_load_u64(const u64* ptr) {
    return __hip_atomic_load(ptr, __ATOMIC_RELAXED, __HIP_MEMORY_SCOPE_AGENT);
}
__device__ __forceinline__ void sc_store_i(int* ptr, int v) {
    __hip_atomic_store(ptr, v, __ATOMIC_RELAXED, __HIP_MEMORY_SCOPE_AGENT);
}
__device__ __forceinline__ int sc_load_i(const int* ptr) {
    return __hip_atomic_load(ptr, __ATOMIC_RELAXED, __HIP_MEMORY_SCOPE_AGENT);
}

// ======================= shared preproc building blocks =======================
struct PreShm {
    float ph[512], mg[512], skey[512], sig[512], vld[512];
    int   sidx[512];
    float ps2[512], ms2[512], vs2[512];
    float pn[50][8], pd[50][8], smoothv[50];
    float gshift, nv;
};

__device__ void bitonic512a(float* skey, int* sidx, int tid, bool act) {
    for (int k = 2; k <= 512; k <<= 1) {
        for (int j = k >> 1; j > 0; j >>= 1) {
            int ixj = tid ^ j;
            if (act && ixj > tid) {
                float ka = skey[tid], kb = skey[ixj];
                int ia = sidx[tid], ib = sidx[ixj];
                bool up = ((tid & k) == 0);
                bool agtb = (ka > kb) || (ka == kb && ia > ib);
                if (agtb == up) {
                    skey[tid] = kb; skey[ixj] = ka;
                    sidx[tid] = ib; sidx[ixj] = ia;
                }
            }
            __syncthreads();
        }
    }
}

template<bool BF>
__device__ void preproc_core(const P& p, PreShm& s, int b, int tid) {
    bool act = tid < 512;
    if (act) {
        float period = 2.0f / ldw<BF>(p.freq, b);
        float t = ldw<BF>(p.lc, (size_t)b * 3 * SS + tid);
        float m = ldw<BF>(p.lc, (size_t)b * 3 * SS + SS + tid);
        float ph0 = fmodf(t, period) / period;
        s.ph[tid] = ph0; s.mg[tid] = m;
        s.skey[tid] = ph0; s.sidx[tid] = tid;
    }
    __syncthreads();
    bitonic512a(s.skey, s.sidx, tid, act);
    if (act) {
        float pc = s.skey[tid];
        float wv[4], mv[4];
        float wsum = 0.f, wm = 0.f;
        const int offs[4] = {-2, -1, 1, 2};
#pragma unroll
        for (int c = 0; c < 4; ++c) {
            int jj = (tid + offs[c]) & 511;
            float d = s.skey[jj] - pc;
            float u = d - 0.5f; u = u - floorf(u);
            float dphi = u - 0.5f;
            float w = 0.75f * (1.0f - dphi * dphi);
            float mm = s.mg[s.sidx[jj]];
            wv[c] = w; mv[c] = mm;
            wsum += w; wm += w * mm;
        }
        float loc = wm / wsum;
        float s2 = 0.f;
#pragma unroll
        for (int c = 0; c < 4; ++c) { float dm = mv[c] - loc; s2 += dm * dm * wv[c]; }
        float scale = sqrtf(s2 / (wsum - 1.0f));
        s.sig[s.sidx[tid]] = loc + 5.0f * scale;
    }
    __syncthreads();
    if (act) s.vld[tid] = (s.mg[tid] > s.sig[tid]) ? 0.0f : 1.0f;
    __syncthreads();
    if (tid == 0) {
        float acc = 0.f;
        for (int i = 0; i < 512; ++i) acc += s.vld[i];
        s.nv = acc;
    }
    {
        int g = tid >> 3, pq = tid & 7;
        if (g < 50) {
            float gv = (float)g * (1.0f / 49.0f);
            float num = 0.f, den = 0.f;
            int s0 = pq * 64;
            for (int ss = s0; ss < s0 + 64; ++ss) {
                float d = gv - s.ph[ss];
                float c = cosf(TWO_PI * d);
                float K = expf((c - 1.0f) * 100.0f);
                float w = s.vld[ss] * K;
                den += w; num += w * s.mg[ss];
            }
            s.pn[g][pq] = num; s.pd[g][pq] = den;
        }
    }
    __syncthreads();
    if (tid < 50) {
        float num = 0.f, den = 0.f;
#pragma unroll
        for (int c = 0; c < 8; ++c) { num += s.pn[tid][c]; den += s.pd[tid][c]; }
        s.smoothv[tid] = num / den;
    }
    __syncthreads();
    if (tid == 0) {
        float best = s.smoothv[0]; int bi = 0;
        for (int g = 1; g < 50; ++g) if (s.smoothv[g] > best) { best = s.smoothv[g]; bi = g; }
        s.gshift = (float)bi * (1.0f / 49.0f);
    }
    __syncthreads();
    if (act) {
        float p2 = s.ph[tid] - s.gshift;
        s.ph[tid] = p2;
        s.skey[tid] = (s.vld[tid] > 0.f) ? p2 : BIGF;
        s.sidx[tid] = tid;
    }
    __syncthreads();
    bitonic512a(s.skey, s.sidx, tid, act);
    if (act) {
        int o = s.sidx[tid];
        s.ps2[tid] = s.ph[o]; s.ms2[tid] = s.mg[o]; s.vs2[tid] = s.vld[o];
    }
    __syncthreads();
}

// ======================= fallback kernel (tiny ws; simple 64x512) =======================
struct ShmOld {
    PreShm pre;
    float h0[512], h1[512];
    float eL[33];
};

template<bool BF>
__device__ void run_old(const P& p, ShmOld& s) {
    int b = blockIdx.x, tid = threadIdx.x;
    preproc_core<BF>(p, s.pre, b, tid);

    int j = tid;
    float wr0[33], wz0[33], wn0[33];
#pragma unroll
    for (int d = 0; d < 33; ++d) {
        wr0[d] = ldw<BF>(p.W[0], (size_t)j * 33 + d);
        wz0[d] = ldw<BF>(p.W[0], ((size_t)j + 512) * 33 + d);
        wn0[d] = ldw<BF>(p.W[0], ((size_t)j + 1024) * 33 + d);
    }
    float bi0r = ldw<BF>(p.W[1], j), bi0z = ldw<BF>(p.W[1], j + 512), bi0n = ldw<BF>(p.W[1], j + 1024);
    float bh0r = ldw<BF>(p.W[3], j), bh0z = ldw<BF>(p.W[3], j + 512), bh0n = ldw<BF>(p.W[3], j + 1024);
    float bi1r = ldw<BF>(p.W[5], j), bi1z = ldw<BF>(p.W[5], j + 512), bi1n = ldw<BF>(p.W[5], j + 1024);
    float bh1r = ldw<BF>(p.W[7], j), bh1z = ldw<BF>(p.W[7], j + 512), bh1n = ldw<BF>(p.W[7], j + 1024);

    s.h0[j] = 0.f; s.h1[j] = 0.f;
    float cacc = 0.f;
    __syncthreads();

    for (int tt = 0; tt < 512; ++tt) {
        if (j < 16) {
            float ang = TWO_PI * s.pre.ps2[tt] * (float)(j + 1);
            float sv, cv; sincosf(ang, &sv, &cv);
            s.eL[j] = cv; s.eL[16 + j] = sv;
        }
        if (j == 32) s.eL[32] = s.pre.ms2[tt];
        __syncthreads();
        float xr = bi0r, xz = bi0z, xn = bi0n;
#pragma unroll
        for (int d = 0; d < 33; ++d) {
            float e = s.eL[d];
            xr += wr0[d] * e; xz += wz0[d] * e; xn += wn0[d] * e;
        }
        float ar = bh0r, az = bh0z, an = bh0n;
        for (int k = 0; k < 512; ++k) {
            float h = s.h0[k];
            ar += ldw<BF>(p.W[2], (size_t)j * 512 + k) * h;
            az += ldw<BF>(p.W[2], ((size_t)j + 512) * 512 + k) * h;
            an += ldw<BF>(p.W[2], ((size_t)j + 1024) * 512 + k) * h;
        }
        float h0prev = s.h0[j];
        float r0 = 1.0f / (1.0f + expf(-(xr + ar)));
        float z0 = 1.0f / (1.0f + expf(-(xz + az)));
        float n0 = tanhf(xn + r0 * an);
        float nh0 = (1.0f - z0) * n0 + z0 * h0prev;
        __syncthreads();
        s.h0[j] = nh0;
        __syncthreads();
        float yr = bi1r, yz = bi1z, yn = bi1n;
        float cr = bh1r, cz = bh1z, cn = bh1n;
        for (int k = 0; k < 512; ++k) {
            float h = s.h0[k], g = s.h1[k];
            yr += ldw<BF>(p.W[4], (size_t)j * 512 + k) * h;
            yz += ldw<BF>(p.W[4], ((size_t)j + 512) * 512 + k) * h;
            yn += ldw<BF>(p.W[4], ((size_t)j + 1024) * 512 + k) * h;
            cr += ldw<BF>(p.W[6], (size_t)j * 512 + k) * g;
            cz += ldw<BF>(p.W[6], ((size_t)j + 512) * 512 + k) * g;
            cn += ldw<BF>(p.W[6], ((size_t)j + 1024) * 512 + k) * g;
        }
        float h1prev = s.h1[j];
        float r1 = 1.0f / (1.0f + expf(-(yr + cr)));
        float z1 = 1.0f / (1.0f + expf(-(yz + cz)));
        float n1 = tanhf(yn + r1 * cn);
        float nh1 = (1.0f - z1) * n1 + z1 * h1prev;
        cacc += s.pre.vs2[tt] * nh1;
        __syncthreads();
        s.h1[j] = nh1;
    }
    __syncthreads();

    s.h0[j] = cacc / s.pre.nv;
    __syncthreads();
    float a1 = ldw<BF>(p.W[9], j);
    for (int k = 0; k < 512; ++k) a1 += ldw<BF>(p.W[8], (size_t)j * 512 + k) * s.h0[k];
    float g = 0.5f * a1 * (1.0f + erff(a1 * 0.70710678118654752440f));
    __syncthreads();
    s.h1[j] = g;
    __syncthreads();
    if (j < 16) {
        float a2 = ldw<BF>(p.W[11], j);
        for (int k = 0; k < 512; ++k) a2 += ldw<BF>(p.W[10], (size_t)j * 512 + k) * s.h1[k];
        if constexpr (BF) ((u16*)p.out)[(size_t)b * 16 + j] = f2b(a2);
        else              ((float*)p.out)[(size_t)b * 16 + j] = a2;
    }
}

__global__ __launch_bounds__(512) void fused_kernel_old(P p) {
    __shared__ ShmOld s;
    if (inputs_are_bf16(p.freq)) run_old<true>(p, s);
    else                         run_old<false>(p, s);
}

// ======================= NEW kernel: batch-parallel GEMM, 64x1024 =======================
struct ShmNew {
    union U {
        float hb[2][4096];      // 2 x 16KB h-tiles [64 k][64 b]
        PreShm pre;
    } u;
    float part[8][6][64];       // partial combine + MLP scratch
    int dead;
};

// grid barrier: store-own-flag + load-only polling; bounded, dead-flag latched.
__device__ __forceinline__ void gbar(int* barf, int bid, int ep, int tid, ShmNew& s) {
    __syncthreads();                 // drains this block's prior VMEM stores
    if (tid == 0) sc_store_i(&barf[bid], ep);
    if (tid < NBK && !s.dead) {
        int it = 0;
        while (sc_load_i(&barf[tid]) < ep) {
            __builtin_amdgcn_s_sleep(1);
            if (++it > 1000000) { s.dead = 1; break; }   // fail loud, once
        }
    }
    __syncthreads();
}

__device__ __forceinline__ void load16(const u64* src, int tid, u64* pv) {
#pragma unroll
    for (int i = 0; i < 16; ++i) pv[i] = sc_load_u64(&src[tid + i * 1024]);
}
__device__ __forceinline__ void wr_tile(float* buf, u64 a, u64 b8, int tid) {
    ((u64*)buf)[tid] = a;
    ((u64*)buf)[tid + 1024] = b8;
}

// 3 gate-row dot partial over one 64-k tile; lane = batch b; weights wave-uniform.
template<bool BF>
__device__ __forceinline__ void dot3_tile(const void* Wbase, int j, int T, int half,
                                          const float* __restrict__ hbT, int b,
                                          float& ar, float& az, float& an) {
    const int k0 = T * 64 + half * 32;
    const int kk0 = half * 32;
    if constexpr (BF) {
        const u16* Wr = (const u16*)Wbase + (size_t)j * 512;
        const u16* Wz = (const u16*)Wbase + ((size_t)j + 512) * 512;
        const u16* Wn = (const u16*)Wbase + ((size_t)j + 1024) * 512;
#pragma unroll
        for (int i = 0; i < 32; i += 8) {
            uint4 wr = *(const uint4*)(Wr + k0 + i);
            uint4 wz = *(const uint4*)(Wz + k0 + i);
            uint4 wn = *(const uint4*)(Wn + k0 + i);
            float h0 = hbT[(kk0 + i + 0) * 64 + b], h1 = hbT[(kk0 + i + 1) * 64 + b];
            float h2 = hbT[(kk0 + i + 2) * 64 + b], h3 = hbT[(kk0 + i + 3) * 64 + b];
            float h4 = hbT[(kk0 + i + 4) * 64 + b], h5 = hbT[(kk0 + i + 5) * 64 + b];
            float h6 = hbT[(kk0 + i + 6) * 64 + b], h7 = hbT[(kk0 + i + 7) * 64 + b];
            ar += blo(wr.x)*h0 + bhi(wr.x)*h1 + blo(wr.y)*h2 + bhi(wr.y)*h3
                + blo(wr.z)*h4 + bhi(wr.z)*h5 + blo(wr.w)*h6 + bhi(wr.w)*h7;
            az += blo(wz.x)*h0 + bhi(wz.x)*h1 + blo(wz.y)*h2 + bhi(wz.y)*h3
                + blo(wz.z)*h4 + bhi(wz.z)*h5 + blo(wz.w)*h6 + bhi(wz.w)*h7;
            an += blo(wn.x)*h0 + bhi(wn.x)*h1 + blo(wn.y)*h2 + bhi(wn.y)*h3
                + blo(wn.z)*h4 + bhi(wn.z)*h5 + blo(wn.w)*h6 + bhi(wn.w)*h7;
        }
    } else {
        const float* Wr = (const float*)Wbase + (size_t)j * 512;
        const float* Wz = (const float*)Wbase + ((size_t)j + 512) * 512;
        const float* Wn = (const float*)Wbase + ((size_t)j + 1024) * 512;
#pragma unroll
        for (int i = 0; i < 32; i += 4) {
            float4 wr = *(const float4*)(Wr + k0 + i);
            float4 wz = *(const float4*)(Wz + k0 + i);
            float4 wn = *(const float4*)(Wn + k0 + i);
            float h0 = hbT[(kk0 + i + 0) * 64 + b], h1 = hbT[(kk0 + i + 1) * 64 + b];
            float h2 = hbT[(kk0 + i + 2) * 64 + b], h3 = hbT[(kk0 + i + 3) * 64 + b];
            ar += wr.x*h0 + wr.y*h1 + wr.z*h2 + wr.w*h3;
            az += wz.x*h0 + wz.y*h1 + wz.z*h2 + wz.w*h3;
            an += wn.x*h0 + wn.y*h1 + wn.z*h2 + wn.w*h3;
        }
    }
}

// one staged pass: prefetch (32 VGPR) -> 8 double-buffered LDS tiles -> dots
template<bool BF>
__device__ __forceinline__ void gemm_pass(const u64* src, const void* Wbase,
                                          int j, int half, int b, int tid,
                                          ShmNew& s, float& ar, float& az, float& an) {
    u64 pv[16];
    load16(src, tid, pv);
    wr_tile(&s.u.hb[0][0], pv[0], pv[1], tid);
    __syncthreads();
#pragma unroll
    for (int T = 0; T < 8; ++T) {
        if (T < 7) wr_tile(&s.u.hb[(T + 1) & 1][0], pv[2 * T + 2], pv[2 * T + 3], tid);
        dot3_tile<BF>(Wbase, j, T, half, &s.u.hb[T & 1][0], b, ar, az, an);
        __syncthreads();
    }
}

template<bool BF>
__device__ void run_new(const P& p, ShmNew& s) {
    const int bid = blockIdx.x;                 // 0..63: batch (preproc) AND j-group
    const int tid = threadIdx.x;                // 0..1023
    const int b   = tid & 63;                   // lane = batch
    const int w   = tid >> 6;                   // wave 0..15
    const int jj  = w & 7;
    const int half = __builtin_amdgcn_readfirstlane(w >> 3);
    const int j   = __builtin_amdgcn_readfirstlane(bid * 8 + jj);

    char*  wsb  = (char*)p.ws;
    int*   barf = (int*)(wsb + BARF_OFF);
    float* nvg  = (float*)(wsb + NVG_OFF);
    float* embg = (float*)(wsb + EMB_OFF);      // [512][33][64]
    float* vs2g = (float*)(wsb + VS2_OFF);      // [512][64]
    u64*   h0q  = (u64*)(wsb + H0G_OFF);        // [2][16384] u64 (= [2][512][64] f32)
    u64*   h1q  = (u64*)(wsb + H1G_OFF);
    float* ctxg = (float*)(wsb + CTX_OFF);      // [512][64]

    if (tid == 0) s.dead = 0;

    // ---- preproc: block bid handles batch bid; publish emb/vs2/nv; zero h(-1) ----
    preproc_core<BF>(p, s.u.pre, bid, tid);
    for (int pi = tid; pi < 512 * 16; pi += 1024) {
        int t = pi >> 4, kk = pi & 15;
        float ang = TWO_PI * s.u.pre.ps2[t] * (float)(kk + 1);
        float sv, cv; sincosf(ang, &sv, &cv);
        sc_store_f(&embg[((size_t)t * 33 + kk) * 64 + bid], cv);
        sc_store_f(&embg[((size_t)t * 33 + 16 + kk) * 64 + bid], sv);
    }
    for (int t = tid; t < 512; t += 1024) {
        sc_store_f(&embg[((size_t)t * 33 + 32) * 64 + bid], s.u.pre.ms2[t]);
        sc_store_f(&vs2g[t * 64 + bid], s.u.pre.vs2[t]);
    }
    if (tid == 0) sc_store_f(&nvg[bid], s.u.pre.nv);
    if (tid < 256) {                             // zero parity-1 h(-1) slices
        sc_store_u64(&h0q[16384 + bid * 256 + tid], 0ull);
        sc_store_u64(&h1q[16384 + bid * 256 + tid], 0ull);
    }
    gbar(barf, bid, 1, tid, s);

    // uniform per-j constants
    float bi0r = ldw<BF>(p.W[1], j), bi0z = ldw<BF>(p.W[1], j + 512), bi0n = ldw<BF>(p.W[1], j + 1024);
    float bh0r = ldw<BF>(p.W[3], j), bh0z = ldw<BF>(p.W[3], j + 512), bh0n = ldw<BF>(p.W[3], j + 1024);
    float bi1r = ldw<BF>(p.W[5], j), bi1z = ldw<BF>(p.W[5], j + 512), bi1n = ldw<BF>(p.W[5], j + 1024);
    float bh1r = ldw<BF>(p.W[7], j), bh1z = ldw<BF>(p.W[7], j + 512), bh1n = ldw<BF>(p.W[7], j + 1024);

    float hp0 = 0.f, hp1 = 0.f, cacc = 0.f;

    for (int t = 0; t < 512; ++t) {
        // ================= P1: h0(t) = GRU0(h0(t-1), emb(t)) =================
        float x0r = 0.f, x0z = 0.f, x0n = 0.f;
        if (w < 8) {                     // x-part from precomputed emb (immutable)
            const float* e0 = embg + (size_t)t * 33 * 64 + b;
            x0r = bi0r; x0z = bi0z; x0n = bi0n;
#pragma unroll
            for (int d = 0; d < 33; ++d) {
                float e = e0[d * 64];
                x0r += ldw<BF>(p.W[0], (size_t)j * 33 + d) * e;
                x0z += ldw<BF>(p.W[0], ((size_t)j + 512) * 33 + d) * e;
                x0n += ldw<BF>(p.W[0], ((size_t)j + 1024) * 33 + d) * e;
            }
        }
        float ar = 0.f, az = 0.f, an = 0.f;
        gemm_pass<BF>(&h0q[((t + 1) & 1) * 16384], p.W[2], j, half, b, tid, s, ar, az, an);
        if (w >= 8) { s.part[jj][0][b] = ar; s.part[jj][1][b] = az; s.part[jj][2][b] = an; }
        __syncthreads();
        if (w < 8) {
            ar += s.part[jj][0][b] + bh0r;
            az += s.part[jj][1][b] + bh0z;
            an += s.part[jj][2][b] + bh0n;
            float r0 = 1.f / (1.f + expf(-(x0r + ar)));
            float z0 = 1.f / (1.f + expf(-(x0z + az)));
            float n0 = tanhf(x0n + r0 * an);
            float nh0 = (1.f - z0) * n0 + z0 * hp0;
            hp0 = nh0;
            float o = __shfl_xor(nh0, 1);
            if (!(b & 1)) sc_store_u64(&h0q[(t & 1) * 16384 + j * 32 + (b >> 1)], pk(nh0, o));
        }
        gbar(barf, bid, t + 2, tid, s);          // single mid-step grid barrier

        // ================= P2: h1(t) = GRU1(h1(t-1), h0(t)) =================
        float yr = 0.f, yz = 0.f, yn = 0.f;
        gemm_pass<BF>(&h0q[(t & 1) * 16384], p.W[4], j, half, b, tid, s, yr, yz, yn);
        float cr = 0.f, cz = 0.f, cn = 0.f;
        gemm_pass<BF>(&h1q[((t + 1) & 1) * 16384], p.W[6], j, half, b, tid, s, cr, cz, cn);
        if (w >= 8) {
            s.part[jj][0][b] = yr; s.part[jj][1][b] = yz; s.part[jj][2][b] = yn;
            s.part[jj][3][b] = cr; s.part[jj][4][b] = cz; s.part[jj][5][b] = cn;
        }
        __syncthreads();
        if (w < 8) {
            yr += s.part[jj][0][b] + bi1r;
            yz += s.part[jj][1][b] + bi1z;
            yn += s.part[jj][2][b] + bi1n;
            cr += s.part[jj][3][b] + bh1r;
            cz += s.part[jj][4][b] + bh1z;
            cn += s.part[jj][5][b] + bh1n;
            float r1 = 1.f / (1.f + expf(-(yr + cr)));
            float z1 = 1.f / (1.f + expf(-(yz + cz)));
            float n1 = tanhf(yn + r1 * cn);
            float nh1 = (1.f - z1) * n1 + z1 * hp1;
            hp1 = nh1;
            cacc += vs2g[t * 64 + b] * nh1;
            float o = __shfl_xor(nh1, 1);
            if (!(b & 1)) sc_store_u64(&h1q[(t & 1) * 16384 + j * 32 + (b >> 1)], pk(nh1, o));
        }
        // no end-of-step barrier: next step's mid barrier carries h1(t)
        // visibility and all WAR hazards (see header comment).
    }

    // ---- ctx publish ----
    if (w < 8) sc_store_f(&ctxg[(size_t)j * 64 + b], cacc / nvg[b]);
    gbar(barf, bid, 514, tid, s);

    // ---- MLP head: block bid handles batch bid ----
    float* ctxL = &s.part[0][0][0];   // 512 floats
    float* gL   = ctxL + 512;         // 512 floats
    if (tid < 512) ctxL[tid] = sc_load_f(&ctxg[(size_t)tid * 64 + bid]);
    __syncthreads();
    if (tid < 512) {
        float a1 = ldw<BF>(p.W[9], tid);
        for (int k = 0; k < 512; ++k) a1 += ldw<BF>(p.W[8], (size_t)tid * 512 + k) * ctxL[k];
        gL[tid] = 0.5f * a1 * (1.f + erff(a1 * 0.70710678118654752440f));
    }
    __syncthreads();
    if (tid < 16) {
        float a2 = ldw<BF>(p.W[11], tid);
        for (int k = 0; k < 512; ++k) a2 += ldw<BF>(p.W[10], (size_t)tid * 512 + k) * gL[k];
        if constexpr (BF) ((u16*)p.out)[(size_t)bid * 16 + tid] = f2b(a2);
        else              ((float*)p.out)[(size_t)bid * 16 + tid] = a2;
    }
}

__global__ __launch_bounds__(1024, 4) void fused_kernel_new(P p) {
    __shared__ ShmNew s;
    if (inputs_are_bf16(p.freq)) run_new<true>(p, s);
    else                         run_new<false>(p, s);
}

extern "C" void kernel_launch(void* const* d_in, const int* in_sizes, int n_in,
                              void* d_out, int out_size, void* d_ws, size_t ws_size,
                              hipStream_t stream) {
    P p;
    p.lc = d_in[0];
    p.freq = d_in[2];
    for (int i = 0; i < 12; ++i) p.W[i] = d_in[3 + i];
    p.out = d_out;
    p.ws = d_ws;
    p.ws_size = (unsigned long long)ws_size;
    if (d_ws && ws_size >= (size_t)NEED_NEW) {
        hipMemsetAsync(d_ws, 0, 4096, stream);    // barrier flags
        fused_kernel_new<<<NBK, 1024, 0, stream>>>(p);
    } else {
        fused_kernel_old<<<64, 512, 0, stream>>>(p);
    }
    (void)in_sizes; (void)n_in; (void)out_size;
}

// Round 7
// 270946.021 us; speedup vs baseline: 1.0234x; 1.0019x over previous
//
#include <hip/hip_runtime.h>

// FoldedAutoencoder — round 9: batch-parallel GEMM, register-budget fit.
// R6 post-mortem: __launch_bounds__(1024,4) did NOT raise the VGPR cap
// (still 64; FETCH/WRITE bit-identical to R5 -> identical spill codegen).
// The 8-tile register prefetch (pv[16] = 32 VGPRs) can never fit a 64-VGPR
// budget next to weights/accumulators -> allocator spills the loop working
// set to scratch = 204 GB HBM writes = the whole runtime.
// Fix: 2-deep pipeline -- prefetch ONE tile (2 x u64 = 4 VGPRs) while
// dotting the current LDS tile. Live set ~55 VGPRs -> fits 64, no spill.
// dot-tile is ~770 cyc/SIMD wall vs ~300 cyc L2 latency -> still covered.
// Summation order / barriers / tile order identical to R6 (passed, absmax 0).

typedef unsigned short u16;
typedef unsigned int u32;
typedef unsigned long long u64;

__device__ __forceinline__ float b2f(u16 u) { return __uint_as_float(((u32)u) << 16); }
__device__ __forceinline__ float blo(u32 u) { return __uint_as_float(u << 16); }
__device__ __forceinline__ float bhi(u32 u) { return __uint_as_float(u & 0xffff0000u); }
__device__ __forceinline__ u16 f2b(float f) {
    u32 x = __float_as_uint(f);
    u32 r = x + 0x7fffu + ((x >> 16) & 1u);   // RNE
    return (u16)(r >> 16);
}
__device__ __forceinline__ u64 pk(float lo, float hi) {
    return ((u64)__float_as_uint(hi) << 32) | (u64)__float_as_uint(lo);
}

#define SS 512
#define TWO_PI 6.28318530717958647692f
#define BIGF 3.402823466e+38f
#define NBK 64

// ---- workspace layout ----
#define BARF_OFF 0                            // 64 ints (memset to 0 each launch)
#define NVG_OFF  4096                         // 64 f32
#define EMB_OFF  8192                         // [512][33][64] f32 = 4,325,376 B
#define VS2_OFF  (EMB_OFF + 4325376)          // [512][64] f32
#define H0G_OFF  (VS2_OFF + 131072)           // [2][512][64] f32
#define H1G_OFF  (H0G_OFF + 262144)
#define CTX_OFF  (H1G_OFF + 262144)           // [512][64] f32
#define NEED_NEW ((unsigned long long)(CTX_OFF + 131072))

struct P {
    const void* lc;     // (B,3,S)
    const void* freq;   // (B,)
    const void* W[12];  // Wih0,bih0,Whh0,bhh0,Wih1,bih1,Whh1,bhh1,Wl1,bl1,Wl2,bl2
    void* out;          // (B,16)
    void* ws;
    unsigned long long ws_size;
};

__device__ __forceinline__ bool inputs_are_bf16(const void* freq) {
    const u16* q = (const u16*)freq;
    bool ok = true;
    for (int i = 0; i < 64; ++i) {
        float v = b2f(q[i]);
        ok = ok && (v >= 0.4f) && (v <= 5.5f);
    }
    return ok;
}

template<bool BF>
__device__ __forceinline__ float ldw(const void* p, size_t i) {
    if constexpr (BF) return b2f(((const u16*)p)[i]);
    else              return ((const float*)p)[i];
}

// agent-scope helpers
__device__ __forceinline__ void sc_store_f(float* ptr, float v) {
    __hip_atomic_store(ptr, v, __ATOMIC_RELAXED, __HIP_MEMORY_SCOPE_AGENT);
}
__device__ __forceinline__ float sc_load_f(const float* ptr) {
    return __hip_atomic_load(ptr, __ATOMIC_RELAXED, __HIP_MEMORY_SCOPE_AGENT);
}
__device__ __forceinline__ void sc_store_u64(u64* ptr, u64 v) {
    __hip_atomic_store(ptr, v, __ATOMIC_RELAXED, __HIP_MEMORY_SCOPE_AGENT);
}
__device__ __forceinline__ u64 sc_load_u64(const u64* ptr) {
    return __hip_atomic_load(ptr, __ATOMIC_RELAXED, __HIP_MEMORY_SCOPE_AGENT);
}
__device__ __forceinline__ void sc_store_i(int* ptr, int v) {
    __hip_atomic_store(ptr, v, __ATOMIC_RELAXED, __HIP_MEMORY_SCOPE_AGENT);
}
__device__ __forceinline__ int sc_load_i(const int* ptr) {
    return __hip_atomic_load(ptr, __ATOMIC_RELAXED, __HIP_MEMORY_SCOPE_AGENT);
}

// ======================= shared preproc building blocks =======================
struct PreShm {
    float ph[512], mg[512], skey[512], sig[512], vld[512];
    int   sidx[512];
    float ps2[512], ms2[512], vs2[512];
    float pn[50][8], pd[50][8], smoothv[50];
    float gshift, nv;
};

__device__ void bitonic512a(float* skey, int* sidx, int tid, bool act) {
    for (int k = 2; k <= 512; k <<= 1) {
        for (int j = k >> 1; j > 0; j >>= 1) {
            int ixj = tid ^ j;
            if (act && ixj > tid) {
                float ka = skey[tid], kb = skey[ixj];
                int ia = sidx[tid], ib = sidx[ixj];
                bool up = ((tid & k) == 0);
                bool agtb = (ka > kb) || (ka == kb && ia > ib);
                if (agtb == up) {
                    skey[tid] = kb; skey[ixj] = ka;
                    sidx[tid] = ib; sidx[ixj] = ia;
                }
            }
            __syncthreads();
        }
    }
}

template<bool BF>
__device__ void preproc_core(const P& p, PreShm& s, int b, int tid) {
    bool act = tid < 512;
    if (act) {
        float period = 2.0f / ldw<BF>(p.freq, b);
        float t = ldw<BF>(p.lc, (size_t)b * 3 * SS + tid);
        float m = ldw<BF>(p.lc, (size_t)b * 3 * SS + SS + tid);
        float ph0 = fmodf(t, period) / period;
        s.ph[tid] = ph0; s.mg[tid] = m;
        s.skey[tid] = ph0; s.sidx[tid] = tid;
    }
    __syncthreads();
    bitonic512a(s.skey, s.sidx, tid, act);
    if (act) {
        float pc = s.skey[tid];
        float wv[4], mv[4];
        float wsum = 0.f, wm = 0.f;
        const int offs[4] = {-2, -1, 1, 2};
#pragma unroll
        for (int c = 0; c < 4; ++c) {
            int jj = (tid + offs[c]) & 511;
            float d = s.skey[jj] - pc;
            float u = d - 0.5f; u = u - floorf(u);
            float dphi = u - 0.5f;
            float w = 0.75f * (1.0f - dphi * dphi);
            float mm = s.mg[s.sidx[jj]];
            wv[c] = w; mv[c] = mm;
            wsum += w; wm += w * mm;
        }
        float loc = wm / wsum;
        float s2 = 0.f;
#pragma unroll
        for (int c = 0; c < 4; ++c) { float dm = mv[c] - loc; s2 += dm * dm * wv[c]; }
        float scale = sqrtf(s2 / (wsum - 1.0f));
        s.sig[s.sidx[tid]] = loc + 5.0f * scale;
    }
    __syncthreads();
    if (act) s.vld[tid] = (s.mg[tid] > s.sig[tid]) ? 0.0f : 1.0f;
    __syncthreads();
    if (tid == 0) {
        float acc = 0.f;
        for (int i = 0; i < 512; ++i) acc += s.vld[i];
        s.nv = acc;
    }
    {
        int g = tid >> 3, pq = tid & 7;
        if (g < 50) {
            float gv = (float)g * (1.0f / 49.0f);
            float num = 0.f, den = 0.f;
            int s0 = pq * 64;
            for (int ss = s0; ss < s0 + 64; ++ss) {
                float d = gv - s.ph[ss];
                float c = cosf(TWO_PI * d);
                float K = expf((c - 1.0f) * 100.0f);
                float w = s.vld[ss] * K;
                den += w; num += w * s.mg[ss];
            }
            s.pn[g][pq] = num; s.pd[g][pq] = den;
        }
    }
    __syncthreads();
    if (tid < 50) {
        float num = 0.f, den = 0.f;
#pragma unroll
        for (int c = 0; c < 8; ++c) { num += s.pn[tid][c]; den += s.pd[tid][c]; }
        s.smoothv[tid] = num / den;
    }
    __syncthreads();
    if (tid == 0) {
        float best = s.smoothv[0]; int bi = 0;
        for (int g = 1; g < 50; ++g) if (s.smoothv[g] > best) { best = s.smoothv[g]; bi = g; }
        s.gshift = (float)bi * (1.0f / 49.0f);
    }
    __syncthreads();
    if (act) {
        float p2 = s.ph[tid] - s.gshift;
        s.ph[tid] = p2;
        s.skey[tid] = (s.vld[tid] > 0.f) ? p2 : BIGF;
        s.sidx[tid] = tid;
    }
    __syncthreads();
    bitonic512a(s.skey, s.sidx, tid, act);
    if (act) {
        int o = s.sidx[tid];
        s.ps2[tid] = s.ph[o]; s.ms2[tid] = s.mg[o]; s.vs2[tid] = s.vld[o];
    }
    __syncthreads();
}

// ======================= fallback kernel (tiny ws; simple 64x512) =======================
struct ShmOld {
    PreShm pre;
    float h0[512], h1[512];
    float eL[33];
};

template<bool BF>
__device__ void run_old(const P& p, ShmOld& s) {
    int b = blockIdx.x, tid = threadIdx.x;
    preproc_core<BF>(p, s.pre, b, tid);

    int j = tid;
    float wr0[33], wz0[33], wn0[33];
#pragma unroll
    for (int d = 0; d < 33; ++d) {
        wr0[d] = ldw<BF>(p.W[0], (size_t)j * 33 + d);
        wz0[d] = ldw<BF>(p.W[0], ((size_t)j + 512) * 33 + d);
        wn0[d] = ldw<BF>(p.W[0], ((size_t)j + 1024) * 33 + d);
    }
    float bi0r = ldw<BF>(p.W[1], j), bi0z = ldw<BF>(p.W[1], j + 512), bi0n = ldw<BF>(p.W[1], j + 1024);
    float bh0r = ldw<BF>(p.W[3], j), bh0z = ldw<BF>(p.W[3], j + 512), bh0n = ldw<BF>(p.W[3], j + 1024);
    float bi1r = ldw<BF>(p.W[5], j), bi1z = ldw<BF>(p.W[5], j + 512), bi1n = ldw<BF>(p.W[5], j + 1024);
    float bh1r = ldw<BF>(p.W[7], j), bh1z = ldw<BF>(p.W[7], j + 512), bh1n = ldw<BF>(p.W[7], j + 1024);

    s.h0[j] = 0.f; s.h1[j] = 0.f;
    float cacc = 0.f;
    __syncthreads();

    for (int tt = 0; tt < 512; ++tt) {
        if (j < 16) {
            float ang = TWO_PI * s.pre.ps2[tt] * (float)(j + 1);
            float sv, cv; sincosf(ang, &sv, &cv);
            s.eL[j] = cv; s.eL[16 + j] = sv;
        }
        if (j == 32) s.eL[32] = s.pre.ms2[tt];
        __syncthreads();
        float xr = bi0r, xz = bi0z, xn = bi0n;
#pragma unroll
        for (int d = 0; d < 33; ++d) {
            float e = s.eL[d];
            xr += wr0[d] * e; xz += wz0[d] * e; xn += wn0[d] * e;
        }
        float ar = bh0r, az = bh0z, an = bh0n;
        for (int k = 0; k < 512; ++k) {
            float h = s.h0[k];
            ar += ldw<BF>(p.W[2], (size_t)j * 512 + k) * h;
            az += ldw<BF>(p.W[2], ((size_t)j + 512) * 512 + k) * h;
            an += ldw<BF>(p.W[2], ((size_t)j + 1024) * 512 + k) * h;
        }
        float h0prev = s.h0[j];
        float r0 = 1.0f / (1.0f + expf(-(xr + ar)));
        float z0 = 1.0f / (1.0f + expf(-(xz + az)));
        float n0 = tanhf(xn + r0 * an);
        float nh0 = (1.0f - z0) * n0 + z0 * h0prev;
        __syncthreads();
        s.h0[j] = nh0;
        __syncthreads();
        float yr = bi1r, yz = bi1z, yn = bi1n;
        float cr = bh1r, cz = bh1z, cn = bh1n;
        for (int k = 0; k < 512; ++k) {
            float h = s.h0[k], g = s.h1[k];
            yr += ldw<BF>(p.W[4], (size_t)j * 512 + k) * h;
            yz += ldw<BF>(p.W[4], ((size_t)j + 512) * 512 + k) * h;
            yn += ldw<BF>(p.W[4], ((size_t)j + 1024) * 512 + k) * h;
            cr += ldw<BF>(p.W[6], (size_t)j * 512 + k) * g;
            cz += ldw<BF>(p.W[6], ((size_t)j + 512) * 512 + k) * g;
            cn += ldw<BF>(p.W[6], ((size_t)j + 1024) * 512 + k) * g;
        }
        float h1prev = s.h1[j];
        float r1 = 1.0f / (1.0f + expf(-(yr + cr)));
        float z1 = 1.0f / (1.0f + expf(-(yz + cz)));
        float n1 = tanhf(yn + r1 * cn);
        float nh1 = (1.0f - z1) * n1 + z1 * h1prev;
        cacc += s.pre.vs2[tt] * nh1;
        __syncthreads();
        s.h1[j] = nh1;
    }
    __syncthreads();

    s.h0[j] = cacc / s.pre.nv;
    __syncthreads();
    float a1 = ldw<BF>(p.W[9], j);
    for (int k = 0; k < 512; ++k) a1 += ldw<BF>(p.W[8], (size_t)j * 512 + k) * s.h0[k];
    float g = 0.5f * a1 * (1.0f + erff(a1 * 0.70710678118654752440f));
    __syncthreads();
    s.h1[j] = g;
    __syncthreads();
    if (j < 16) {
        float a2 = ldw<BF>(p.W[11], j);
        for (int k = 0; k < 512; ++k) a2 += ldw<BF>(p.W[10], (size_t)j * 512 + k) * s.h1[k];
        if constexpr (BF) ((u16*)p.out)[(size_t)b * 16 + j] = f2b(a2);
        else              ((float*)p.out)[(size_t)b * 16 + j] = a2;
    }
}

__global__ __launch_bounds__(512) void fused_kernel_old(P p) {
    __shared__ ShmOld s;
    if (inputs_are_bf16(p.freq)) run_old<true>(p, s);
    else                         run_old<false>(p, s);
}

// ======================= NEW kernel: batch-parallel GEMM, 64x1024 =======================
struct ShmNew {
    union U {
        float hb[2][4096];      // 2 x 16KB h-tiles [64 k][64 b]
        PreShm pre;
    } u;
    float part[8][6][64];       // partial combine + MLP scratch
    int dead;
};

// grid barrier: store-own-flag + load-only polling; bounded, dead-flag latched.
__device__ __forceinline__ void gbar(int* barf, int bid, int ep, int tid, ShmNew& s) {
    __syncthreads();                 // drains this block's prior VMEM stores
    if (tid == 0) sc_store_i(&barf[bid], ep);
    if (tid < NBK && !s.dead) {
        int it = 0;
        while (sc_load_i(&barf[tid]) < ep) {
            __builtin_amdgcn_s_sleep(1);
            if (++it > 1000000) { s.dead = 1; break; }   // fail loud, once
        }
    }
    __syncthreads();
}

__device__ __forceinline__ void wr_tile(float* buf, u64 a, u64 b8, int tid) {
    ((u64*)buf)[tid] = a;
    ((u64*)buf)[tid + 1024] = b8;
}

// 3 gate-row dot partial over one 64-k tile; lane = batch b; weights wave-uniform (SGPR).
template<bool BF>
__device__ __forceinline__ void dot3_tile(const void* Wbase, int j, int T, int half,
                                          const float* __restrict__ hbT, int b,
                                          float& ar, float& az, float& an) {
    const int k0 = T * 64 + half * 32;
    const int kk0 = half * 32;
    if constexpr (BF) {
        const u16* Wr = (const u16*)Wbase + (size_t)j * 512;
        const u16* Wz = (const u16*)Wbase + ((size_t)j + 512) * 512;
        const u16* Wn = (const u16*)Wbase + ((size_t)j + 1024) * 512;
#pragma unroll
        for (int i = 0; i < 32; i += 8) {
            uint4 wr = *(const uint4*)(Wr + k0 + i);
            uint4 wz = *(const uint4*)(Wz + k0 + i);
            uint4 wn = *(const uint4*)(Wn + k0 + i);
            float h0 = hbT[(kk0 + i + 0) * 64 + b], h1 = hbT[(kk0 + i + 1) * 64 + b];
            float h2 = hbT[(kk0 + i + 2) * 64 + b], h3 = hbT[(kk0 + i + 3) * 64 + b];
            float h4 = hbT[(kk0 + i + 4) * 64 + b], h5 = hbT[(kk0 + i + 5) * 64 + b];
            float h6 = hbT[(kk0 + i + 6) * 64 + b], h7 = hbT[(kk0 + i + 7) * 64 + b];
            ar += blo(wr.x)*h0 + bhi(wr.x)*h1 + blo(wr.y)*h2 + bhi(wr.y)*h3
                + blo(wr.z)*h4 + bhi(wr.z)*h5 + blo(wr.w)*h6 + bhi(wr.w)*h7;
            az += blo(wz.x)*h0 + bhi(wz.x)*h1 + blo(wz.y)*h2 + bhi(wz.y)*h3
                + blo(wz.z)*h4 + bhi(wz.z)*h5 + blo(wz.w)*h6 + bhi(wz.w)*h7;
            an += blo(wn.x)*h0 + bhi(wn.x)*h1 + blo(wn.y)*h2 + bhi(wn.y)*h3
                + blo(wn.z)*h4 + bhi(wn.z)*h5 + blo(wn.w)*h6 + bhi(wn.w)*h7;
        }
    } else {
        const float* Wr = (const float*)Wbase + (size_t)j * 512;
        const float* Wz = (const float*)Wbase + ((size_t)j + 512) * 512;
        const float* Wn = (const float*)Wbase + ((size_t)j + 1024) * 512;
#pragma unroll
        for (int i = 0; i < 32; i += 4) {
            float4 wr = *(const float4*)(Wr + k0 + i);
            float4 wz = *(const float4*)(Wz + k0 + i);
            float4 wn = *(const float4*)(Wn + k0 + i);
            float h0 = hbT[(kk0 + i + 0) * 64 + b], h1 = hbT[(kk0 + i + 1) * 64 + b];
            float h2 = hbT[(kk0 + i + 2) * 64 + b], h3 = hbT[(kk0 + i + 3) * 64 + b];
            ar += wr.x*h0 + wr.y*h1 + wr.z*h2 + wr.w*h3;
            az += wz.x*h0 + wz.y*h1 + wz.z*h2 + wz.w*h3;
            an += wn.x*h0 + wn.y*h1 + wn.z*h2 + wn.w*h3;
        }
    }
}

// one staged pass, 2-deep pipeline: LDS tile T being dotted while tile T+1
// sits in 2 u64 regs (4 VGPRs). Tile/summation order identical to R6.
template<bool BF>
__device__ __forceinline__ void gemm_pass(const u64* src, const void* Wbase,
                                          int j, int half, int b, int tid,
                                          ShmNew& s, float& ar, float& az, float& an) {
    u64 a0 = sc_load_u64(&src[tid]);
    u64 a1 = sc_load_u64(&src[tid + 1024]);
    wr_tile(&s.u.hb[0][0], a0, a1, tid);
    a0 = sc_load_u64(&src[tid + 2048]);           // prefetch tile 1
    a1 = sc_load_u64(&src[tid + 3072]);
    __syncthreads();
#pragma unroll
    for (int T = 0; T < 8; ++T) {
        if (T < 7) {
            wr_tile(&s.u.hb[(T + 1) & 1][0], a0, a1, tid);
            if (T < 6) {
                a0 = sc_load_u64(&src[tid + (T + 2) * 2048]);
                a1 = sc_load_u64(&src[tid + (T + 2) * 2048 + 1024]);
            }
        }
        dot3_tile<BF>(Wbase, j, T, half, &s.u.hb[T & 1][0], b, ar, az, an);
        __syncthreads();
    }
}

template<bool BF>
__device__ void run_new(const P& p, ShmNew& s) {
    const int bid = blockIdx.x;                 // 0..63: batch (preproc) AND j-group
    const int tid = threadIdx.x;                // 0..1023
    const int b   = tid & 63;                   // lane = batch
    const int w   = tid >> 6;                   // wave 0..15
    const int jj  = w & 7;
    const int half = __builtin_amdgcn_readfirstlane(w >> 3);
    const int j   = __builtin_amdgcn_readfirstlane(bid * 8 + jj);

    char*  wsb  = (char*)p.ws;
    int*   barf = (int*)(wsb + BARF_OFF);
    float* nvg  = (float*)(wsb + NVG_OFF);
    float* embg = (float*)(wsb + EMB_OFF);      // [512][33][64]
    float* vs2g = (float*)(wsb + VS2_OFF);      // [512][64]
    u64*   h0q  = (u64*)(wsb + H0G_OFF);        // [2][16384] u64 (= [2][512][64] f32)
    u64*   h1q  = (u64*)(wsb + H1G_OFF);
    float* ctxg = (float*)(wsb + CTX_OFF);      // [512][64]

    if (tid == 0) s.dead = 0;

    // ---- preproc: block bid handles batch bid; publish emb/vs2/nv; zero h(-1) ----
    preproc_core<BF>(p, s.u.pre, bid, tid);
    for (int pi = tid; pi < 512 * 16; pi += 1024) {
        int t = pi >> 4, kk = pi & 15;
        float ang = TWO_PI * s.u.pre.ps2[t] * (float)(kk + 1);
        float sv, cv; sincosf(ang, &sv, &cv);
        sc_store_f(&embg[((size_t)t * 33 + kk) * 64 + bid], cv);
        sc_store_f(&embg[((size_t)t * 33 + 16 + kk) * 64 + bid], sv);
    }
    for (int t = tid; t < 512; t += 1024) {
        sc_store_f(&embg[((size_t)t * 33 + 32) * 64 + bid], s.u.pre.ms2[t]);
        sc_store_f(&vs2g[t * 64 + bid], s.u.pre.vs2[t]);
    }
    if (tid == 0) sc_store_f(&nvg[bid], s.u.pre.nv);
    if (tid < 256) {                             // zero parity-1 h(-1) slices
        sc_store_u64(&h0q[16384 + bid * 256 + tid], 0ull);
        sc_store_u64(&h1q[16384 + bid * 256 + tid], 0ull);
    }
    gbar(barf, bid, 1, tid, s);

    // uniform per-j constants (SGPRs)
    float bi0r = ldw<BF>(p.W[1], j), bi0z = ldw<BF>(p.W[1], j + 512), bi0n = ldw<BF>(p.W[1], j + 1024);
    float bh0r = ldw<BF>(p.W[3], j), bh0z = ldw<BF>(p.W[3], j + 512), bh0n = ldw<BF>(p.W[3], j + 1024);
    float bi1r = ldw<BF>(p.W[5], j), bi1z = ldw<BF>(p.W[5], j + 512), bi1n = ldw<BF>(p.W[5], j + 1024);
    float bh1r = ldw<BF>(p.W[7], j), bh1z = ldw<BF>(p.W[7], j + 512), bh1n = ldw<BF>(p.W[7], j + 1024);

    float hp0 = 0.f, hp1 = 0.f, cacc = 0.f;

    for (int t = 0; t < 512; ++t) {
        // ================= P1: h0(t) = GRU0(h0(t-1), emb(t)) =================
        float x0r = 0.f, x0z = 0.f, x0n = 0.f;
        if (w < 8) {                     // x-part from precomputed emb (immutable)
            const float* e0 = embg + (size_t)t * 33 * 64 + b;
            x0r = bi0r; x0z = bi0z; x0n = bi0n;
#pragma unroll
            for (int d = 0; d < 33; ++d) {
                float e = e0[d * 64];
                x0r += ldw<BF>(p.W[0], (size_t)j * 33 + d) * e;
                x0z += ldw<BF>(p.W[0], ((size_t)j + 512) * 33 + d) * e;
                x0n += ldw<BF>(p.W[0], ((size_t)j + 1024) * 33 + d) * e;
            }
        }
        float ar = 0.f, az = 0.f, an = 0.f;
        gemm_pass<BF>(&h0q[((t + 1) & 1) * 16384], p.W[2], j, half, b, tid, s, ar, az, an);
        if (w >= 8) { s.part[jj][0][b] = ar; s.part[jj][1][b] = az; s.part[jj][2][b] = an; }
        __syncthreads();
        if (w < 8) {
            ar += s.part[jj][0][b] + bh0r;
            az += s.part[jj][1][b] + bh0z;
            an += s.part[jj][2][b] + bh0n;
            float r0 = 1.f / (1.f + expf(-(x0r + ar)));
            float z0 = 1.f / (1.f + expf(-(x0z + az)));
            float n0 = tanhf(x0n + r0 * an);
            float nh0 = (1.f - z0) * n0 + z0 * hp0;
            hp0 = nh0;
            float o = __shfl_xor(nh0, 1);
            if (!(b & 1)) sc_store_u64(&h0q[(t & 1) * 16384 + j * 32 + (b >> 1)], pk(nh0, o));
        }
        gbar(barf, bid, t + 2, tid, s);          // single mid-step grid barrier

        // ================= P2: h1(t) = GRU1(h1(t-1), h0(t)) =================
        float yr = 0.f, yz = 0.f, yn = 0.f;
        gemm_pass<BF>(&h0q[(t & 1) * 16384], p.W[4], j, half, b, tid, s, yr, yz, yn);
        float cr = 0.f, cz = 0.f, cn = 0.f;
        gemm_pass<BF>(&h1q[((t + 1) & 1) * 16384], p.W[6], j, half, b, tid, s, cr, cz, cn);
        if (w >= 8) {
            s.part[jj][0][b] = yr; s.part[jj][1][b] = yz; s.part[jj][2][b] = yn;
            s.part[jj][3][b] = cr; s.part[jj][4][b] = cz; s.part[jj][5][b] = cn;
        }
        __syncthreads();
        if (w < 8) {
            yr += s.part[jj][0][b] + bi1r;
            yz += s.part[jj][1][b] + bi1z;
            yn += s.part[jj][2][b] + bi1n;
            cr += s.part[jj][3][b] + bh1r;
            cz += s.part[jj][4][b] + bh1z;
            cn += s.part[jj][5][b] + bh1n;
            float r1 = 1.f / (1.f + expf(-(yr + cr)));
            float z1 = 1.f / (1.f + expf(-(yz + cz)));
            float n1 = tanhf(yn + r1 * cn);
            float nh1 = (1.f - z1) * n1 + z1 * hp1;
            hp1 = nh1;
            cacc += vs2g[t * 64 + b] * nh1;
            float o = __shfl_xor(nh1, 1);
            if (!(b & 1)) sc_store_u64(&h1q[(t & 1) * 16384 + j * 32 + (b >> 1)], pk(nh1, o));
        }
        // no end-of-step barrier: next step's mid barrier carries h1(t)
        // visibility and all WAR hazards.
    }

    // ---- ctx publish ----
    if (w < 8) sc_store_f(&ctxg[(size_t)j * 64 + b], cacc / nvg[b]);
    gbar(barf, bid, 514, tid, s);

    // ---- MLP head: block bid handles batch bid ----
    float* ctxL = &s.part[0][0][0];   // 512 floats
    float* gL   = ctxL + 512;         // 512 floats
    if (tid < 512) ctxL[tid] = sc_load_f(&ctxg[(size_t)tid * 64 + bid]);
    __syncthreads();
    if (tid < 512) {
        float a1 = ldw<BF>(p.W[9], tid);
        for (int k = 0; k < 512; ++k) a1 += ldw<BF>(p.W[8], (size_t)tid * 512 + k) * ctxL[k];
        gL[tid] = 0.5f * a1 * (1.f + erff(a1 * 0.70710678118654752440f));
    }
    __syncthreads();
    if (tid < 16) {
        float a2 = ldw<BF>(p.W[11], tid);
        for (int k = 0; k < 512; ++k) a2 += ldw<BF>(p.W[10], (size_t)tid * 512 + k) * gL[k];
        if constexpr (BF) ((u16*)p.out)[(size_t)bid * 16 + tid] = f2b(a2);
        else              ((float*)p.out)[(size_t)bid * 16 + tid] = a2;
    }
}

__global__ __launch_bounds__(1024, 1) void fused_kernel_new(P p) {
    __shared__ ShmNew s;
    if (inputs_are_bf16(p.freq)) run_new<true>(p, s);
    else                         run_new<false>(p, s);
}

extern "C" void kernel_launch(void* const* d_in, const int* in_sizes, int n_in,
                              void* d_out, int out_size, void* d_ws, size_t ws_size,
                              hipStream_t stream) {
    P p;
    p.lc = d_in[0];
    p.freq = d_in[2];
    for (int i = 0; i < 12; ++i) p.W[i] = d_in[3 + i];
    p.out = d_out;
    p.ws = d_ws;
    p.ws_size = (unsigned long long)ws_size;
    if (d_ws && ws_size >= (size_t)NEED_NEW) {
        hipMemsetAsync(d_ws, 0, 4096, stream);    // barrier flags
        fused_kernel_new<<<NBK, 1024, 0, stream>>>(p);
    } else {
        fused_kernel_old<<<64, 512, 0, stream>>>(p);
    }
    (void)in_sizes; (void)n_in; (void)out_size;
}

// Round 8
// 14865.253 us; speedup vs baseline: 18.6529x; 18.2268x over previous
//
#include <hip/hip_runtime.h>

// FoldedAutoencoder — round 10: 3-stage pipeline split (A|B|C), R1 block shape.
// R5-R7 post-mortem: the 1024-thread grid-barrier GEMM kernel has an
// unexplained 204 GB EA-write pathology invariant to codegen changes;
// abandoned. This round re-expresses the traffic theory in R1's proven shape:
// 192 blocks x 512 threads. Per batch: block A = W_hh0 + x-part (h0 chain),
// block B = W_ih1 @ h0(t), block C = W_hh1 (h1 chain) + ctx + MLP head.
// Each block streams 3.1 MB/step (1/3 of R1) through its L1. Streams are
// ONE-WAY depth-4 rings in ws (sc-store -> vmcnt(0) -> flag; load-only poll;
// dead-latch bounded) — the R3-correctness-verified protocol; no grid
// barrier, no RMW, no two-way exchange. Summation order bit-identical to R1.
// Fallback: ws < need (11.7 MB f32 / 7.0 MB bf16) -> R1 PAN kernel (41.5 ms).

typedef unsigned short u16;
typedef unsigned int u32;
typedef unsigned long long u64;

__device__ __forceinline__ float b2f(u16 u) { return __uint_as_float(((u32)u) << 16); }
__device__ __forceinline__ float blo(u32 u) { return __uint_as_float(u << 16); }
__device__ __forceinline__ float bhi(u32 u) { return __uint_as_float(u & 0xffff0000u); }
__device__ __forceinline__ u16 f2b(float f) {
    u32 x = __float_as_uint(f);
    u32 r = x + 0x7fffu + ((x >> 16) & 1u);   // RNE
    return (u16)(r >> 16);
}

#define SS 512
#define TWO_PI 6.28318530717958647692f
#define BIGF 3.402823466e+38f
#define PANEL_ELEMS (1536 * 512)
#define FLAGS_BYTES 32768
#define RD 4                       // ring depth (power of 2)

struct P {
    const void* lc;
    const void* freq;
    const void* W[12];  // Wih0,bih0,Whh0,bhh0,Wih1,bih1,Whh1,bhh1,Wl1,bl1,Wl2,bl2
    void* out;
    void* ws;
    unsigned long long ws_size;
};

__device__ __forceinline__ bool inputs_are_bf16(const void* freq) {
    const u16* q = (const u16*)freq;
    bool ok = true;
    for (int i = 0; i < 64; ++i) {
        float v = b2f(q[i]);
        ok = ok && (v >= 0.4f) && (v <= 5.5f);
    }
    return ok;
}

template<bool BF>
__device__ __forceinline__ float ldw(const void* p, size_t i) {
    if constexpr (BF) return b2f(((const u16*)p)[i]);
    else              return ((const float*)p)[i];
}
template<bool BF>
__device__ __forceinline__ const void* rowp(const void* base, int row) {
    if constexpr (BF) return (const void*)((const u16*)base + (size_t)row * 512);
    else              return (const void*)((const float*)base + (size_t)row * 512);
}

// agent-scope helpers (R3-verified protocol primitives)
__device__ __forceinline__ void sc_store_f(float* ptr, float v) {
    __hip_atomic_store(ptr, v, __ATOMIC_RELAXED, __HIP_MEMORY_SCOPE_AGENT);
}
__device__ __forceinline__ float sc_load_f(const float* ptr) {
    return __hip_atomic_load(ptr, __ATOMIC_RELAXED, __HIP_MEMORY_SCOPE_AGENT);
}
__device__ __forceinline__ void sc_store_i(int* ptr, int v) {
    __hip_atomic_store(ptr, v, __ATOMIC_RELAXED, __HIP_MEMORY_SCOPE_AGENT);
}
__device__ __forceinline__ int sc_load_i(const int* ptr) {
    return __hip_atomic_load(ptr, __ATOMIC_RELAXED, __HIP_MEMORY_SCOPE_AGENT);
}

// bounded load-only poll; dead-latch in LDS (caller = tid 0 only)
__device__ __forceinline__ void waitge(const int* f, int v, int* dead) {
    if (*dead) return;
    int it = 0;
    while (sc_load_i(f) < v) {
        __builtin_amdgcn_s_sleep(1);
        if (++it > 2000000) { *dead = 1; break; }
    }
}

// ---------- k-major panels (R1-verified layout) ----------
// f32:  float4 panel[(k>>2)*1536 + row]   bf16: uint4 panel[(k>>3)*1536 + row]
template<bool BF>
__device__ void build_panel_one(const void* W, int tid, char* panbase) {
    if constexpr (BF) {
        const uint4* Ws = (const uint4*)W;
        uint4* panel = (uint4*)panbase;
        for (int i = tid; i < 1536 * 64; i += 512) {
            int r = i >> 6, k8 = i & 63;
            panel[(size_t)k8 * 1536 + r] = Ws[i];
        }
    } else {
        const float4* Ws = (const float4*)W;
        float4* panel = (float4*)panbase;
        for (int i = tid; i < 1536 * 128; i += 512) {
            int r = i >> 7, k4 = i & 127;
            panel[(size_t)k4 * 1536 + r] = Ws[i];
        }
    }
}

template<bool BF>
__device__ __forceinline__ void tridot_panel(const void* panel, int j,
                                             const float* __restrict__ sh,
                                             float& ar, float& az, float& an) {
    if constexpr (BF) {
        const uint4* pr = (const uint4*)panel + j;
        const uint4* pz = pr + 512;
        const uint4* pn = pr + 1024;
        for (int k0 = 0; k0 < 512; k0 += 8) {
            size_t o = (size_t)(k0 >> 3) * 1536;
            float4 h0 = *(const float4*)&sh[k0];
            float4 h1 = *(const float4*)&sh[k0 + 4];
            uint4 a = pr[o], c = pz[o], d = pn[o];
            ar += blo(a.x) * h0.x + bhi(a.x) * h0.y + blo(a.y) * h0.z + bhi(a.y) * h0.w
                + blo(a.z) * h1.x + bhi(a.z) * h1.y + blo(a.w) * h1.z + bhi(a.w) * h1.w;
            az += blo(c.x) * h0.x + bhi(c.x) * h0.y + blo(c.y) * h0.z + bhi(c.y) * h0.w
                + blo(c.z) * h1.x + bhi(c.z) * h1.y + blo(c.w) * h1.z + bhi(c.w) * h1.w;
            an += blo(d.x) * h0.x + bhi(d.x) * h0.y + blo(d.y) * h0.z + bhi(d.y) * h0.w
                + blo(d.z) * h1.x + bhi(d.z) * h1.y + blo(d.w) * h1.z + bhi(d.w) * h1.w;
        }
    } else {
        const float4* pr = (const float4*)panel + j;
        const float4* pz = pr + 512;
        const float4* pn = pr + 1024;
        for (int k0 = 0; k0 < 512; k0 += 8) {
            size_t o = (size_t)(k0 >> 2) * 1536;
            float4 h0 = *(const float4*)&sh[k0];
            float4 h1 = *(const float4*)&sh[k0 + 4];
            float4 a0 = pr[o], a1 = pr[o + 1536];
            float4 c0 = pz[o], c1 = pz[o + 1536];
            float4 d0 = pn[o], d1 = pn[o + 1536];
            ar += a0.x * h0.x + a0.y * h0.y + a0.z * h0.z + a0.w * h0.w
                + a1.x * h1.x + a1.y * h1.y + a1.z * h1.z + a1.w * h1.w;
            az += c0.x * h0.x + c0.y * h0.y + c0.z * h0.z + c0.w * h0.w
                + c1.x * h1.x + c1.y * h1.y + c1.z * h1.z + c1.w * h1.w;
            an += d0.x * h0.x + d0.y * h0.y + d0.z * h0.z + d0.w * h0.w
                + d1.x * h1.x + d1.y * h1.y + d1.z * h1.z + d1.w * h1.w;
        }
    }
}

template<bool BF>
__device__ __forceinline__ float dot512(const void* vr, const float* __restrict__ sh) {
    float acc = 0.f;
    if constexpr (BF) {
        const u32* pr = (const u32*)vr;
        for (int k0 = 0; k0 < 512; k0 += 8) {
            float4 h0 = *(const float4*)&sh[k0];
            float4 h1 = *(const float4*)&sh[k0 + 4];
            uint4 a = *(const uint4*)(pr + (k0 >> 1));
            acc += blo(a.x) * h0.x + bhi(a.x) * h0.y + blo(a.y) * h0.z + bhi(a.y) * h0.w
                 + blo(a.z) * h1.x + bhi(a.z) * h1.y + blo(a.w) * h1.z + bhi(a.w) * h1.w;
        }
    } else {
        const float* pr = (const float*)vr;
        for (int k0 = 0; k0 < 512; k0 += 8) {
            float4 h0 = *(const float4*)&sh[k0];
            float4 h1 = *(const float4*)&sh[k0 + 4];
            float4 a0 = *(const float4*)(pr + k0), a1 = *(const float4*)(pr + k0 + 4);
            acc += a0.x * h0.x + a0.y * h0.y + a0.z * h0.z + a0.w * h0.w
                 + a1.x * h1.x + a1.y * h1.y + a1.z * h1.z + a1.w * h1.w;
        }
    }
    return acc;
}

// ======================= preproc (R1-verified, 512 threads) =======================
struct PreShm {
    float ph[512], mg[512], skey[512], sig[512], vld[512];
    int   sidx[512];
    float ps2[512], ms2[512], vs2[512];
    float pn[50][8], pd[50][8], smoothv[50];
    float gshift, nv;
};

__device__ void bitonic512(float* skey, int* sidx, int tid) {
    for (int k = 2; k <= 512; k <<= 1) {
        for (int j = k >> 1; j > 0; j >>= 1) {
            int ixj = tid ^ j;
            if (ixj > tid) {
                float ka = skey[tid], kb = skey[ixj];
                int ia = sidx[tid], ib = sidx[ixj];
                bool up = ((tid & k) == 0);
                bool agtb = (ka > kb) || (ka == kb && ia > ib);
                if (agtb == up) {
                    skey[tid] = kb; skey[ixj] = ka;
                    sidx[tid] = ib; sidx[ixj] = ia;
                }
            }
            __syncthreads();
        }
    }
}

template<bool BF>
__device__ void preproc_core(const P& p, PreShm& s, int b, int tid) {
    float period = 2.0f / ldw<BF>(p.freq, b);
    float t = ldw<BF>(p.lc, (size_t)b * 3 * SS + tid);
    float m = ldw<BF>(p.lc, (size_t)b * 3 * SS + SS + tid);
    float ph0 = fmodf(t, period) / period;
    s.ph[tid] = ph0; s.mg[tid] = m;
    s.skey[tid] = ph0; s.sidx[tid] = tid;
    __syncthreads();
    bitonic512(s.skey, s.sidx, tid);
    {
        float pc = s.skey[tid];
        float wv[4], mv[4];
        float wsum = 0.f, wm = 0.f;
        const int offs[4] = {-2, -1, 1, 2};
#pragma unroll
        for (int c = 0; c < 4; ++c) {
            int jj = (tid + offs[c]) & 511;
            float d = s.skey[jj] - pc;
            float u = d - 0.5f; u = u - floorf(u);
            float dphi = u - 0.5f;
            float w = 0.75f * (1.0f - dphi * dphi);
            float mm = s.mg[s.sidx[jj]];
            wv[c] = w; mv[c] = mm;
            wsum += w; wm += w * mm;
        }
        float loc = wm / wsum;
        float s2 = 0.f;
#pragma unroll
        for (int c = 0; c < 4; ++c) { float dm = mv[c] - loc; s2 += dm * dm * wv[c]; }
        float scale = sqrtf(s2 / (wsum - 1.0f));
        s.sig[s.sidx[tid]] = loc + 5.0f * scale;
    }
    __syncthreads();
    s.vld[tid] = (s.mg[tid] > s.sig[tid]) ? 0.0f : 1.0f;
    __syncthreads();
    if (tid == 0) {
        float acc = 0.f;
        for (int i = 0; i < 512; ++i) acc += s.vld[i];
        s.nv = acc;
    }
    {
        int g = tid >> 3, pq = tid & 7;
        if (g < 50) {
            float gv = (float)g * (1.0f / 49.0f);
            float num = 0.f, den = 0.f;
            int s0 = pq * 64;
            for (int ss = s0; ss < s0 + 64; ++ss) {
                float d = gv - s.ph[ss];
                float c = cosf(TWO_PI * d);
                float K = expf((c - 1.0f) * 100.0f);
                float w = s.vld[ss] * K;
                den += w; num += w * s.mg[ss];
            }
            s.pn[g][pq] = num; s.pd[g][pq] = den;
        }
    }
    __syncthreads();
    if (tid < 50) {
        float num = 0.f, den = 0.f;
#pragma unroll
        for (int c = 0; c < 8; ++c) { num += s.pn[tid][c]; den += s.pd[tid][c]; }
        s.smoothv[tid] = num / den;
    }
    __syncthreads();
    if (tid == 0) {
        float best = s.smoothv[0]; int bi = 0;
        for (int g = 1; g < 50; ++g) if (s.smoothv[g] > best) { best = s.smoothv[g]; bi = g; }
        s.gshift = (float)bi * (1.0f / 49.0f);
    }
    __syncthreads();
    float p2 = s.ph[tid] - s.gshift;
    s.ph[tid] = p2;
    s.skey[tid] = (s.vld[tid] > 0.f) ? p2 : BIGF;
    s.sidx[tid] = tid;
    __syncthreads();
    bitonic512(s.skey, s.sidx, tid);
    {
        int o = s.sidx[tid];
        s.ps2[tid] = s.ph[o]; s.ms2[tid] = s.mg[o]; s.vs2[tid] = s.vld[o];
    }
    __syncthreads();
}

// ======================= shared LDS =======================
struct ShmU {
    union {
        struct { PreShm pre; float h0[512], h1[512], eL[34]; } a;   // A + old path
        struct { float h0loc[512]; } b;
        struct { float vs2[512], h1[512], cg[1024], nv; } c;
    } u;
    int dead;
};

// ======================= OLD fallback (R1 PAN, 64x512, 41.5 ms verified) ============
template<bool BF, bool PAN>
__device__ void run_all(const P& p, ShmU& S) {
    PreShm& pre = S.u.a.pre;
    float* h0 = S.u.a.h0;
    float* h1 = S.u.a.h1;
    float* eL = S.u.a.eL;
    int b = blockIdx.x, tid = threadIdx.x;
    char* panbase = (char*)p.ws + FLAGS_BYTES;
    const size_t PMAT = (size_t)PANEL_ELEMS * (BF ? 2 : 4);

    if constexpr (PAN) {
        build_panel_one<BF>(p.W[2], tid, panbase);
        build_panel_one<BF>(p.W[4], tid, panbase + PMAT);
        build_panel_one<BF>(p.W[6], tid, panbase + 2 * PMAT);
        __threadfence();
    }
    preproc_core<BF>(p, pre, b, tid);

    int j = tid;
    float wr0[33], wz0[33], wn0[33];
#pragma unroll
    for (int d = 0; d < 33; ++d) {
        wr0[d] = ldw<BF>(p.W[0], (size_t)j * 33 + d);
        wz0[d] = ldw<BF>(p.W[0], ((size_t)j + 512) * 33 + d);
        wn0[d] = ldw<BF>(p.W[0], ((size_t)j + 1024) * 33 + d);
    }
    float bi0r = ldw<BF>(p.W[1], j), bi0z = ldw<BF>(p.W[1], j + 512), bi0n = ldw<BF>(p.W[1], j + 1024);
    float bh0r = ldw<BF>(p.W[3], j), bh0z = ldw<BF>(p.W[3], j + 512), bh0n = ldw<BF>(p.W[3], j + 1024);
    float bi1r = ldw<BF>(p.W[5], j), bi1z = ldw<BF>(p.W[5], j + 512), bi1n = ldw<BF>(p.W[5], j + 1024);
    float bh1r = ldw<BF>(p.W[7], j), bh1z = ldw<BF>(p.W[7], j + 512), bh1n = ldw<BF>(p.W[7], j + 1024);

    const void* pan0  = (const void*)panbase;
    const void* pan1x = (const void*)(panbase + PMAT);
    const void* pan1h = (const void*)(panbase + 2 * PMAT);
    const void *w0r = rowp<BF>(p.W[2], j), *w0z = rowp<BF>(p.W[2], j + 512), *w0n = rowp<BF>(p.W[2], j + 1024);
    const void *x1r = rowp<BF>(p.W[4], j), *x1z = rowp<BF>(p.W[4], j + 512), *x1n = rowp<BF>(p.W[4], j + 1024);
    const void *w1r = rowp<BF>(p.W[6], j), *w1z = rowp<BF>(p.W[6], j + 512), *w1n = rowp<BF>(p.W[6], j + 1024);

    h0[j] = 0.f; h1[j] = 0.f;
    float cacc = 0.f;
    __syncthreads();

    for (int tt = 0; tt < 512; ++tt) {
        if (j < 16) {
            float ang = TWO_PI * pre.ps2[tt] * (float)(j + 1);
            float sv, cv; sincosf(ang, &sv, &cv);
            eL[j] = cv; eL[16 + j] = sv;
        }
        if (j == 32) eL[32] = pre.ms2[tt];
        __syncthreads();
        float xr = bi0r, xz = bi0z, xn = bi0n;
#pragma unroll
        for (int d = 0; d < 33; ++d) {
            float e = eL[d];
            xr += wr0[d] * e; xz += wz0[d] * e; xn += wn0[d] * e;
        }
        float ar = bh0r, az = bh0z, an = bh0n;
        if constexpr (PAN) tridot_panel<BF>(pan0, j, h0, ar, az, an);
        else {
            for (int k = 0; k < 512; ++k) {
                float h = h0[k];
                ar += ldw<BF>(w0r, k) * h; az += ldw<BF>(w0z, k) * h; an += ldw<BF>(w0n, k) * h;
            }
        }
        float h0prev = h0[j];
        float r0 = 1.0f / (1.0f + expf(-(xr + ar)));
        float z0 = 1.0f / (1.0f + expf(-(xz + az)));
        float n0 = tanhf(xn + r0 * an);
        float nh0 = (1.0f - z0) * n0 + z0 * h0prev;
        __syncthreads();
        h0[j] = nh0;
        __syncthreads();
        float yr = bi1r, yz = bi1z, yn = bi1n;
        float cr = bh1r, cz = bh1z, cn = bh1n;
        if constexpr (PAN) {
            tridot_panel<BF>(pan1x, j, h0, yr, yz, yn);
            tridot_panel<BF>(pan1h, j, h1, cr, cz, cn);
        } else {
            for (int k = 0; k < 512; ++k) {
                float h = h0[k], g = h1[k];
                yr += ldw<BF>(x1r, k) * h; yz += ldw<BF>(x1z, k) * h; yn += ldw<BF>(x1n, k) * h;
                cr += ldw<BF>(w1r, k) * g; cz += ldw<BF>(w1z, k) * g; cn += ldw<BF>(w1n, k) * g;
            }
        }
        float h1prev = h1[j];
        float r1 = 1.0f / (1.0f + expf(-(yr + cr)));
        float z1 = 1.0f / (1.0f + expf(-(yz + cz)));
        float n1 = tanhf(yn + r1 * cn);
        float nh1 = (1.0f - z1) * n1 + z1 * h1prev;
        cacc += pre.vs2[tt] * nh1;
        __syncthreads();
        h1[j] = nh1;
    }
    __syncthreads();

    h0[j] = cacc / pre.nv;
    __syncthreads();
    float a1 = ldw<BF>(p.W[9], j) + dot512<BF>(rowp<BF>(p.W[8], j), h0);
    float g = 0.5f * a1 * (1.0f + erff(a1 * 0.70710678118654752440f));
    __syncthreads();
    h1[j] = g;
    __syncthreads();
    if (j < 16) {
        float a2 = ldw<BF>(p.W[11], j) + dot512<BF>(rowp<BF>(p.W[10], j), h1);
        if constexpr (BF) ((u16*)p.out)[(size_t)b * 16 + j] = f2b(a2);
        else              ((float*)p.out)[(size_t)b * 16 + j] = a2;
    }
}

__global__ __launch_bounds__(512) void fused_kernel_old(P p) {
    __shared__ ShmU S;
    bool bf = inputs_are_bf16(p.freq);
    u64 PMAT = bf ? 1572864ull : 3145728ull;
    bool pan = (p.ws && p.ws_size >= (u64)FLAGS_BYTES + 3 * PMAT);
    if (bf) { if (pan) run_all<true, true>(p, S);  else run_all<true, false>(p, S); }
    else    { if (pan) run_all<false, true>(p, S); else run_all<false, false>(p, S); }
}

// ======================= NEW: 3-stage pipeline, 192 x 512 =======================
// flags (int idx, 64B padded): progA[b]=b*16, progBh=1024+b*16, progBy=2048+b*16,
//                              progC=3072+b*16, preDone=4096+b*16

template<bool BF>
__device__ void runA(const P& p, ShmU& S, int b, int tid,
                     char* panbase, float* h0r, float* vs2g, float* nvg, int* flags) {
    build_panel_one<BF>(p.W[2], tid, panbase);     // own panel: W_hh0
    __threadfence();
    preproc_core<BF>(p, S.u.a.pre, b, tid);
    // publish vs2 + nv for C
    sc_store_f(&vs2g[(size_t)b * 512 + tid], S.u.a.pre.vs2[tid]);
    if (tid == 0) sc_store_f(&nvg[b], S.u.a.pre.nv);
    asm volatile("s_waitcnt vmcnt(0)" ::: "memory");
    __syncthreads();
    if (tid == 0) { S.dead = 0; sc_store_i(&flags[4096 + b * 16], 1); }

    int j = tid;
    float wr0[33], wz0[33], wn0[33];
#pragma unroll
    for (int d = 0; d < 33; ++d) {
        wr0[d] = ldw<BF>(p.W[0], (size_t)j * 33 + d);
        wz0[d] = ldw<BF>(p.W[0], ((size_t)j + 512) * 33 + d);
        wn0[d] = ldw<BF>(p.W[0], ((size_t)j + 1024) * 33 + d);
    }
    float bi0r = ldw<BF>(p.W[1], j), bi0z = ldw<BF>(p.W[1], j + 512), bi0n = ldw<BF>(p.W[1], j + 1024);
    float bh0r = ldw<BF>(p.W[3], j), bh0z = ldw<BF>(p.W[3], j + 512), bh0n = ldw<BF>(p.W[3], j + 1024);

    float* h0 = S.u.a.h0;
    float* eL = S.u.a.eL;
    h0[j] = 0.f;
    __syncthreads();

    for (int t = 0; t < 512; ++t) {
        if (j < 16) {
            float ang = TWO_PI * S.u.a.pre.ps2[t] * (float)(j + 1);
            float sv, cv; sincosf(ang, &sv, &cv);
            eL[j] = cv; eL[16 + j] = sv;
        }
        if (j == 32) eL[32] = S.u.a.pre.ms2[t];
        __syncthreads();
        float xr = bi0r, xz = bi0z, xn = bi0n;
#pragma unroll
        for (int d = 0; d < 33; ++d) {
            float e = eL[d];
            xr += wr0[d] * e; xz += wz0[d] * e; xn += wn0[d] * e;
        }
        float ar = bh0r, az = bh0z, an = bh0n;
        tridot_panel<BF>(panbase, j, h0, ar, az, an);
        float h0prev = h0[j];
        float r0 = 1.0f / (1.0f + expf(-(xr + ar)));
        float z0 = 1.0f / (1.0f + expf(-(xz + az)));
        float n0 = tanhf(xn + r0 * an);
        float nh0 = (1.0f - z0) * n0 + z0 * h0prev;
        __syncthreads();                      // h0(t-1) reads done
        h0[j] = nh0;
        if (tid == 0 && t >= RD) waitge(&flags[1024 + b * 16], t - RD + 1, &S.dead);
        __syncthreads();                      // h0 ready + ring slot free
        sc_store_f(&h0r[((size_t)b * RD + (t & (RD - 1))) * 512 + j], nh0);
        asm volatile("s_waitcnt vmcnt(0)" ::: "memory");
        __syncthreads();
        if (tid == 0) sc_store_i(&flags[b * 16], t + 1);
    }
}

template<bool BF>
__device__ void runB(const P& p, ShmU& S, int b, int tid,
                     char* panbase, float* h0r, float* yrng, int* flags) {
    build_panel_one<BF>(p.W[4], tid, panbase);     // own panel: W_ih1
    __threadfence();
    if (tid == 0) S.dead = 0;
    __syncthreads();

    int j = tid;
    float bi1r = ldw<BF>(p.W[5], j), bi1z = ldw<BF>(p.W[5], j + 512), bi1n = ldw<BF>(p.W[5], j + 1024);
    float* h0loc = S.u.b.h0loc;

    for (int t = 0; t < 512; ++t) {
        if (tid == 0) {
            waitge(&flags[b * 16], t + 1, &S.dead);                       // h0(t) available
            if (t >= RD) waitge(&flags[3072 + b * 16], t - RD + 1, &S.dead);  // y slot free
        }
        __syncthreads();
        h0loc[tid] = sc_load_f(&h0r[((size_t)b * RD + (t & (RD - 1))) * 512 + tid]);
        __syncthreads();
        if (tid == 0) sc_store_i(&flags[1024 + b * 16], t + 1);           // h0 slot consumed
        float yr = bi1r, yz = bi1z, yn = bi1n;
        tridot_panel<BF>(panbase, j, h0loc, yr, yz, yn);
        float* slot = &yrng[((size_t)b * RD + (t & (RD - 1))) * 1536];
        sc_store_f(&slot[j], yr);
        sc_store_f(&slot[512 + j], yz);
        sc_store_f(&slot[1024 + j], yn);
        asm volatile("s_waitcnt vmcnt(0)" ::: "memory");
        __syncthreads();
        if (tid == 0) sc_store_i(&flags[2048 + b * 16], t + 1);           // y(t) published
    }
}

template<bool BF>
__device__ void runC(const P& p, ShmU& S, int b, int tid,
                     char* panbase, float* yrng, float* vs2g, float* nvg, int* flags) {
    build_panel_one<BF>(p.W[6], tid, panbase);     // own panel: W_hh1
    __threadfence();
    if (tid == 0) S.dead = 0;
    __syncthreads();
    if (tid == 0) waitge(&flags[4096 + b * 16], 1, &S.dead);   // preproc done
    __syncthreads();
    S.u.c.vs2[tid] = sc_load_f(&vs2g[(size_t)b * 512 + tid]);
    if (tid == 0) S.u.c.nv = sc_load_f(&nvg[b]);
    S.u.c.h1[tid] = 0.f;
    __syncthreads();

    int j = tid;
    float bh1r = ldw<BF>(p.W[7], j), bh1z = ldw<BF>(p.W[7], j + 512), bh1n = ldw<BF>(p.W[7], j + 1024);
    float* h1 = S.u.c.h1;
    float cacc = 0.f;

    for (int t = 0; t < 512; ++t) {
        if (tid == 0) waitge(&flags[2048 + b * 16], t + 1, &S.dead);      // y(t) ready
        __syncthreads();
        const float* slot = &yrng[((size_t)b * RD + (t & (RD - 1))) * 1536];
        float yr = sc_load_f(&slot[j]);
        float yz = sc_load_f(&slot[512 + j]);
        float yn = sc_load_f(&slot[1024 + j]);
        float cr = bh1r, cz = bh1z, cn = bh1n;
        tridot_panel<BF>(panbase, j, h1, cr, cz, cn);
        float h1prev = h1[j];
        float r1 = 1.0f / (1.0f + expf(-(yr + cr)));
        float z1 = 1.0f / (1.0f + expf(-(yz + cz)));
        float n1 = tanhf(yn + r1 * cn);
        float nh1 = (1.0f - z1) * n1 + z1 * h1prev;
        cacc += S.u.c.vs2[t] * nh1;
        __syncthreads();                      // h1(t-1) reads done
        h1[j] = nh1;
        if (tid == 0) sc_store_i(&flags[3072 + b * 16], t + 1);           // y slot consumed
        __syncthreads();                      // h1 ready for next step
    }

    // ---- ctx + MLP head (all local) ----
    float* ctxL = &S.u.c.cg[0];
    float* gL   = &S.u.c.cg[512];
    ctxL[j] = cacc / S.u.c.nv;
    __syncthreads();
    float a1 = ldw<BF>(p.W[9], j) + dot512<BF>(rowp<BF>(p.W[8], j), ctxL);
    float g = 0.5f * a1 * (1.0f + erff(a1 * 0.70710678118654752440f));
    __syncthreads();
    gL[j] = g;
    __syncthreads();
    if (j < 16) {
        float a2 = ldw<BF>(p.W[11], j) + dot512<BF>(rowp<BF>(p.W[10], j), gL);
        if constexpr (BF) ((u16*)p.out)[(size_t)b * 16 + j] = f2b(a2);
        else              ((float*)p.out)[(size_t)b * 16 + j] = a2;
    }
}

template<bool BF>
__device__ void run_pipe(const P& p, ShmU& S) {
    const int bid = blockIdx.x;
    const int role = bid % 3, b = bid / 3;
    const int tid = threadIdx.x;

    char* wsb = (char*)p.ws;
    int* flags = (int*)wsb;
    const size_t PMAT = (size_t)PANEL_ELEMS * (BF ? 2 : 4);
    char* pan0  = wsb + FLAGS_BYTES;
    char* pan1x = pan0 + PMAT;
    char* pan1h = pan0 + 2 * PMAT;
    float* h0r  = (float*)(pan0 + 3 * PMAT);                 // [64][RD][512]
    float* yrng = h0r + (size_t)64 * RD * 512;               // [64][RD][1536]
    float* vs2g = yrng + (size_t)64 * RD * 1536;             // [64][512]
    float* nvg  = vs2g + (size_t)64 * 512;                   // [64]

    if (role == 0)      runA<BF>(p, S, b, tid, pan0, h0r, vs2g, nvg, flags);
    else if (role == 1) runB<BF>(p, S, b, tid, pan1x, h0r, yrng, flags);
    else                runC<BF>(p, S, b, tid, pan1h, yrng, vs2g, nvg, flags);
}

__global__ __launch_bounds__(512) void fused_kernel_pipe(P p) {
    __shared__ ShmU S;
    if (inputs_are_bf16(p.freq)) run_pipe<true>(p, S);
    else                         run_pipe<false>(p, S);
}

extern "C" void kernel_launch(void* const* d_in, const int* in_sizes, int n_in,
                              void* d_out, int out_size, void* d_ws, size_t ws_size,
                              hipStream_t stream) {
    P p;
    p.lc = d_in[0];
    p.freq = d_in[2];
    for (int i = 0; i < 12; ++i) p.W[i] = d_in[3 + i];
    p.out = d_out;
    p.ws = d_ws;
    p.ws_size = (unsigned long long)ws_size;

    // need (f32): 32768 + 9437184 + 524288 + 1572864 + 131072 + 4096 = 11702272
    // need (bf16): 32768 + 4718592 + 524288 + 1572864 + 131072 + 4096 = 6983680
    // we can't probe dtype on host; require the larger (f32) bound.
    const size_t need_pipe = 32768ull + 9437184ull + 524288ull + 1572864ull + 131072ull + 4096ull;
    if (d_ws && ws_size >= need_pipe) {
        hipMemsetAsync(d_ws, 0, FLAGS_BYTES, stream);
        fused_kernel_pipe<<<192, 512, 0, stream>>>(p);
    } else {
        fused_kernel_old<<<64, 512, 0, stream>>>(p);
    }
    (void)in_sizes; (void)n_in; (void)out_size;
}

// Round 9
// 14314.070 us; speedup vs baseline: 19.3711x; 1.0385x over previous
//
#include <hip/hip_runtime.h>

// FoldedAutoencoder — round 11: 6-way split (3 roles x 2 row-halves, 2 batches
// per group), piece-clustered XCD mapping.
// R8 passed at 14.9 ms: pipeline works; bottleneck = per-CU panel stream
// (3.1 MB/step through one CU's ~144 GB/s L1-fill) + L2 thrash (3 roles/XCD
// = 9.4 MB > 4 MiB). This round: each block owns a HALF panel (1.57 MB/step)
// serving 2 batches (256 rows x 2 batches = 512 thr); cross-half h0/h1 and
// y flow via depth-2 one-way rings (R8-verified protocol: sc-store ->
// vmcnt(0) -> flag; load-only poll; bounded dead-latch). piece = bid&7 (<6)
// so all 32 blocks sharing a piece land on one XCD (bid%8 round-robin) ->
// panel L2-resident. Summation order bit-identical to R8 (full-k dots).
// Fallback: ws < 11.44 MB -> R1 PAN kernel (41.5 ms verified).

typedef unsigned short u16;
typedef unsigned int u32;
typedef unsigned long long u64;

__device__ __forceinline__ float b2f(u16 u) { return __uint_as_float(((u32)u) << 16); }
__device__ __forceinline__ float blo(u32 u) { return __uint_as_float(u << 16); }
__device__ __forceinline__ float bhi(u32 u) { return __uint_as_float(u & 0xffff0000u); }
__device__ __forceinline__ u16 f2b(float f) {
    u32 x = __float_as_uint(f);
    u32 r = x + 0x7fffu + ((x >> 16) & 1u);   // RNE
    return (u16)(r >> 16);
}

#define SS 512
#define TWO_PI 6.28318530717958647692f
#define BIGF 3.402823466e+38f
#define PANEL_ELEMS (1536 * 512)
#define FLAGS_BYTES 32768
#define FL(g, f) (((g) * 16 + (f)) * 16)
// flag ids
#define F_A 0
#define F_B 2
#define F_C 4
#define G_A 6
#define G_B 8
#define G_C 10
#define F_PRE 12
#define F_CTX 14

struct P {
    const void* lc;
    const void* freq;
    const void* W[12];  // Wih0,bih0,Whh0,bhh0,Wih1,bih1,Whh1,bhh1,Wl1,bl1,Wl2,bl2
    void* out;
    void* ws;
    unsigned long long ws_size;
};

__device__ __forceinline__ bool inputs_are_bf16(const void* freq) {
    const u16* q = (const u16*)freq;
    bool ok = true;
    for (int i = 0; i < 64; ++i) {
        float v = b2f(q[i]);
        ok = ok && (v >= 0.4f) && (v <= 5.5f);
    }
    return ok;
}

template<bool BF>
__device__ __forceinline__ float ldw(const void* p, size_t i) {
    if constexpr (BF) return b2f(((const u16*)p)[i]);
    else              return ((const float*)p)[i];
}
template<bool BF>
__device__ __forceinline__ const void* rowp(const void* base, int row) {
    if constexpr (BF) return (const void*)((const u16*)base + (size_t)row * 512);
    else              return (const void*)((const float*)base + (size_t)row * 512);
}

// agent-scope helpers (verified protocol primitives)
__device__ __forceinline__ void sc_store_f(float* ptr, float v) {
    __hip_atomic_store(ptr, v, __ATOMIC_RELAXED, __HIP_MEMORY_SCOPE_AGENT);
}
__device__ __forceinline__ float sc_load_f(const float* ptr) {
    return __hip_atomic_load(ptr, __ATOMIC_RELAXED, __HIP_MEMORY_SCOPE_AGENT);
}
__device__ __forceinline__ void sc_store_i(int* ptr, int v) {
    __hip_atomic_store(ptr, v, __ATOMIC_RELAXED, __HIP_MEMORY_SCOPE_AGENT);
}
__device__ __forceinline__ int sc_load_i(const int* ptr) {
    return __hip_atomic_load(ptr, __ATOMIC_RELAXED, __HIP_MEMORY_SCOPE_AGENT);
}
__device__ __forceinline__ void waitge(const int* f, int v, int* dead) {
    if (*dead) return;
    int it = 0;
    while (sc_load_i(f) < v) {
        __builtin_amdgcn_s_sleep(1);
        if (++it > 2000000) { *dead = 1; break; }
    }
}

// ---------- panels ----------
// FULL panel (old path): f32 float4 panel[(k>>2)*1536 + gr], bf16 uint4 [(k>>3)*1536 + gr]
template<bool BF>
__device__ void build_panel_one(const void* W, int tid, char* panbase) {
    if constexpr (BF) {
        const uint4* Ws = (const uint4*)W;
        uint4* panel = (uint4*)panbase;
        for (int i = tid; i < 1536 * 64; i += 512) {
            int r = i >> 6, k8 = i & 63;
            panel[(size_t)k8 * 1536 + r] = Ws[i];
        }
    } else {
        const float4* Ws = (const float4*)W;
        float4* panel = (float4*)panbase;
        for (int i = tid; i < 1536 * 128; i += 512) {
            int r = i >> 7, k4 = i & 127;
            panel[(size_t)k4 * 1536 + r] = Ws[i];
        }
    }
}
// HALF panel piece: 768 gate-rows (3 gates x 256 rows of `half`), k-major stride 768
template<bool BF>
__device__ void build_piece(const void* W, int half, int tid, char* panbase) {
    if constexpr (BF) {
        const uint4* Ws = (const uint4*)W;
        uint4* panel = (uint4*)panbase;
        for (int i = tid; i < 768 * 64; i += 512) {
            int r768 = i >> 6, k8 = i & 63;
            int g3 = r768 >> 8, r = r768 & 255;
            int srcrow = g3 * 512 + half * 256 + r;
            panel[(size_t)k8 * 768 + r768] = Ws[(size_t)srcrow * 64 + k8];
        }
    } else {
        const float4* Ws = (const float4*)W;
        float4* panel = (float4*)panbase;
        for (int i = tid; i < 768 * 128; i += 512) {
            int r768 = i >> 7, k4 = i & 127;
            int g3 = r768 >> 8, r = r768 & 255;
            int srcrow = g3 * 512 + half * 256 + r;
            panel[(size_t)k4 * 768 + r768] = Ws[(size_t)srcrow * 128 + k4];
        }
    }
}

template<bool BF>
__device__ __forceinline__ void tridot_panel(const void* panel, int j,
                                             const float* __restrict__ sh,
                                             float& ar, float& az, float& an) {
    if constexpr (BF) {
        const uint4* pr = (const uint4*)panel + j;
        const uint4* pz = pr + 512;
        const uint4* pn = pr + 1024;
        for (int k0 = 0; k0 < 512; k0 += 8) {
            size_t o = (size_t)(k0 >> 3) * 1536;
            float4 h0 = *(const float4*)&sh[k0];
            float4 h1 = *(const float4*)&sh[k0 + 4];
            uint4 a = pr[o], c = pz[o], d = pn[o];
            ar += blo(a.x) * h0.x + bhi(a.x) * h0.y + blo(a.y) * h0.z + bhi(a.y) * h0.w
                + blo(a.z) * h1.x + bhi(a.z) * h1.y + blo(a.w) * h1.z + bhi(a.w) * h1.w;
            az += blo(c.x) * h0.x + bhi(c.x) * h0.y + blo(c.y) * h0.z + bhi(c.y) * h0.w
                + blo(c.z) * h1.x + bhi(c.z) * h1.y + blo(c.w) * h1.z + bhi(c.w) * h1.w;
            an += blo(d.x) * h0.x + bhi(d.x) * h0.y + blo(d.y) * h0.z + bhi(d.y) * h0.w
                + blo(d.z) * h1.x + bhi(d.z) * h1.y + blo(d.w) * h1.z + bhi(d.w) * h1.w;
        }
    } else {
        const float4* pr = (const float4*)panel + j;
        const float4* pz = pr + 512;
        const float4* pn = pr + 1024;
        for (int k0 = 0; k0 < 512; k0 += 8) {
            size_t o = (size_t)(k0 >> 2) * 1536;
            float4 h0 = *(const float4*)&sh[k0];
            float4 h1 = *(const float4*)&sh[k0 + 4];
            float4 a0 = pr[o], a1 = pr[o + 1536];
            float4 c0 = pz[o], c1 = pz[o + 1536];
            float4 d0 = pn[o], d1 = pn[o + 1536];
            ar += a0.x * h0.x + a0.y * h0.y + a0.z * h0.z + a0.w * h0.w
                + a1.x * h1.x + a1.y * h1.y + a1.z * h1.z + a1.w * h1.w;
            az += c0.x * h0.x + c0.y * h0.y + c0.z * h0.z + c0.w * h0.w
                + c1.x * h1.x + c1.y * h1.y + c1.z * h1.z + c1.w * h1.w;
            an += d0.x * h0.x + d0.y * h0.y + d0.z * h0.z + d0.w * h0.w
                + d1.x * h1.x + d1.y * h1.y + d1.z * h1.z + d1.w * h1.w;
        }
    }
}

template<bool BF>
__device__ __forceinline__ void tridot_piece(const void* panel, int r,
                                             const float* __restrict__ sh,
                                             float& ar, float& az, float& an) {
    if constexpr (BF) {
        const uint4* pr = (const uint4*)panel + r;
        const uint4* pz = pr + 256;
        const uint4* pn = pr + 512;
        for (int k0 = 0; k0 < 512; k0 += 8) {
            size_t o = (size_t)(k0 >> 3) * 768;
            float4 h0 = *(const float4*)&sh[k0];
            float4 h1 = *(const float4*)&sh[k0 + 4];
            uint4 a = pr[o], c = pz[o], d = pn[o];
            ar += blo(a.x) * h0.x + bhi(a.x) * h0.y + blo(a.y) * h0.z + bhi(a.y) * h0.w
                + blo(a.z) * h1.x + bhi(a.z) * h1.y + blo(a.w) * h1.z + bhi(a.w) * h1.w;
            az += blo(c.x) * h0.x + bhi(c.x) * h0.y + blo(c.y) * h0.z + bhi(c.y) * h0.w
                + blo(c.z) * h1.x + bhi(c.z) * h1.y + blo(c.w) * h1.z + bhi(c.w) * h1.w;
            an += blo(d.x) * h0.x + bhi(d.x) * h0.y + blo(d.y) * h0.z + bhi(d.y) * h0.w
                + blo(d.z) * h1.x + bhi(d.z) * h1.y + blo(d.w) * h1.z + bhi(d.w) * h1.w;
        }
    } else {
        const float4* pr = (const float4*)panel + r;
        const float4* pz = pr + 256;
        const float4* pn = pr + 512;
        for (int k0 = 0; k0 < 512; k0 += 8) {
            size_t o = (size_t)(k0 >> 2) * 768;
            float4 h0 = *(const float4*)&sh[k0];
            float4 h1 = *(const float4*)&sh[k0 + 4];
            float4 a0 = pr[o], a1 = pr[o + 768];
            float4 c0 = pz[o], c1 = pz[o + 768];
            float4 d0 = pn[o], d1 = pn[o + 768];
            ar += a0.x * h0.x + a0.y * h0.y + a0.z * h0.z + a0.w * h0.w
                + a1.x * h1.x + a1.y * h1.y + a1.z * h1.z + a1.w * h1.w;
            az += c0.x * h0.x + c0.y * h0.y + c0.z * h0.z + c0.w * h0.w
                + c1.x * h1.x + c1.y * h1.y + c1.z * h1.z + c1.w * h1.w;
            an += d0.x * h0.x + d0.y * h0.y + d0.z * h0.z + d0.w * h0.w
                + d1.x * h1.x + d1.y * h1.y + d1.z * h1.z + d1.w * h1.w;
        }
    }
}

template<bool BF>
__device__ __forceinline__ float dot512(const void* vr, const float* __restrict__ sh) {
    float acc = 0.f;
    if constexpr (BF) {
        const u32* pr = (const u32*)vr;
        for (int k0 = 0; k0 < 512; k0 += 8) {
            float4 h0 = *(const float4*)&sh[k0];
            float4 h1 = *(const float4*)&sh[k0 + 4];
            uint4 a = *(const uint4*)(pr + (k0 >> 1));
            acc += blo(a.x) * h0.x + bhi(a.x) * h0.y + blo(a.y) * h0.z + bhi(a.y) * h0.w
                 + blo(a.z) * h1.x + bhi(a.z) * h1.y + blo(a.w) * h1.z + bhi(a.w) * h1.w;
        }
    } else {
        const float* pr = (const float*)vr;
        for (int k0 = 0; k0 < 512; k0 += 8) {
            float4 h0 = *(const float4*)&sh[k0];
            float4 h1 = *(const float4*)&sh[k0 + 4];
            float4 a0 = *(const float4*)(pr + k0), a1 = *(const float4*)(pr + k0 + 4);
            acc += a0.x * h0.x + a0.y * h0.y + a0.z * h0.z + a0.w * h0.w
                 + a1.x * h1.x + a1.y * h1.y + a1.z * h1.z + a1.w * h1.w;
        }
    }
    return acc;
}

// ======================= preproc (verified, 512 threads) =======================
struct PreShm {
    float ph[512], mg[512], skey[512], sig[512], vld[512];
    int   sidx[512];
    float ps2[512], ms2[512], vs2[512];
    float pn[50][8], pd[50][8], smoothv[50];
    float gshift, nv;
};

__device__ void bitonic512(float* skey, int* sidx, int tid) {
    for (int k = 2; k <= 512; k <<= 1) {
        for (int j = k >> 1; j > 0; j >>= 1) {
            int ixj = tid ^ j;
            if (ixj > tid) {
                float ka = skey[tid], kb = skey[ixj];
                int ia = sidx[tid], ib = sidx[ixj];
                bool up = ((tid & k) == 0);
                bool agtb = (ka > kb) || (ka == kb && ia > ib);
                if (agtb == up) {
                    skey[tid] = kb; skey[ixj] = ka;
                    sidx[tid] = ib; sidx[ixj] = ia;
                }
            }
            __syncthreads();
        }
    }
}

template<bool BF>
__device__ void preproc_core(const P& p, PreShm& s, int b, int tid) {
    float period = 2.0f / ldw<BF>(p.freq, b);
    float t = ldw<BF>(p.lc, (size_t)b * 3 * SS + tid);
    float m = ldw<BF>(p.lc, (size_t)b * 3 * SS + SS + tid);
    float ph0 = fmodf(t, period) / period;
    s.ph[tid] = ph0; s.mg[tid] = m;
    s.skey[tid] = ph0; s.sidx[tid] = tid;
    __syncthreads();
    bitonic512(s.skey, s.sidx, tid);
    {
        float pc = s.skey[tid];
        float wv[4], mv[4];
        float wsum = 0.f, wm = 0.f;
        const int offs[4] = {-2, -1, 1, 2};
#pragma unroll
        for (int c = 0; c < 4; ++c) {
            int jj = (tid + offs[c]) & 511;
            float d = s.skey[jj] - pc;
            float u = d - 0.5f; u = u - floorf(u);
            float dphi = u - 0.5f;
            float w = 0.75f * (1.0f - dphi * dphi);
            float mm = s.mg[s.sidx[jj]];
            wv[c] = w; mv[c] = mm;
            wsum += w; wm += w * mm;
        }
        float loc = wm / wsum;
        float s2 = 0.f;
#pragma unroll
        for (int c = 0; c < 4; ++c) { float dm = mv[c] - loc; s2 += dm * dm * wv[c]; }
        float scale = sqrtf(s2 / (wsum - 1.0f));
        s.sig[s.sidx[tid]] = loc + 5.0f * scale;
    }
    __syncthreads();
    s.vld[tid] = (s.mg[tid] > s.sig[tid]) ? 0.0f : 1.0f;
    __syncthreads();
    if (tid == 0) {
        float acc = 0.f;
        for (int i = 0; i < 512; ++i) acc += s.vld[i];
        s.nv = acc;
    }
    {
        int g = tid >> 3, pq = tid & 7;
        if (g < 50) {
            float gv = (float)g * (1.0f / 49.0f);
            float num = 0.f, den = 0.f;
            int s0 = pq * 64;
            for (int ss = s0; ss < s0 + 64; ++ss) {
                float d = gv - s.ph[ss];
                float c = cosf(TWO_PI * d);
                float K = expf((c - 1.0f) * 100.0f);
                float w = s.vld[ss] * K;
                den += w; num += w * s.mg[ss];
            }
            s.pn[g][pq] = num; s.pd[g][pq] = den;
        }
    }
    __syncthreads();
    if (tid < 50) {
        float num = 0.f, den = 0.f;
#pragma unroll
        for (int c = 0; c < 8; ++c) { num += s.pn[tid][c]; den += s.pd[tid][c]; }
        s.smoothv[tid] = num / den;
    }
    __syncthreads();
    if (tid == 0) {
        float best = s.smoothv[0]; int bi = 0;
        for (int g = 1; g < 50; ++g) if (s.smoothv[g] > best) { best = s.smoothv[g]; bi = g; }
        s.gshift = (float)bi * (1.0f / 49.0f);
    }
    __syncthreads();
    float p2 = s.ph[tid] - s.gshift;
    s.ph[tid] = p2;
    s.skey[tid] = (s.vld[tid] > 0.f) ? p2 : BIGF;
    s.sidx[tid] = tid;
    __syncthreads();
    bitonic512(s.skey, s.sidx, tid);
    {
        int o = s.sidx[tid];
        s.ps2[tid] = s.ph[o]; s.ms2[tid] = s.mg[o]; s.vs2[tid] = s.vld[o];
    }
    __syncthreads();
}

// ======================= LDS =======================
struct ShmA { PreShm pre; float psb[2][512], msb[2][512]; float h0L[1024]; float eL[2][34]; };
struct ShmB { float h0loc[1024]; };
struct ShmC { float h1L[1024]; float vs2L[2][512]; float nvL[2]; float ctxL[512], gL[512]; };
struct ShmOldA { PreShm pre; float h0[512], h1[512], eL[34]; };
struct ShmU {
    union { ShmA a; ShmB b; ShmC c; ShmOldA o; } u;
    int dead;
};

// ======================= OLD fallback (R1 PAN, 64x512) =======================
template<bool BF, bool PAN>
__device__ void run_all(const P& p, ShmU& S) {
    PreShm& pre = S.u.o.pre;
    float* h0 = S.u.o.h0;
    float* h1 = S.u.o.h1;
    float* eL = S.u.o.eL;
    int b = blockIdx.x, tid = threadIdx.x;
    char* panbase = (char*)p.ws + FLAGS_BYTES;
    const size_t PMAT = (size_t)PANEL_ELEMS * (BF ? 2 : 4);

    if constexpr (PAN) {
        build_panel_one<BF>(p.W[2], tid, panbase);
        build_panel_one<BF>(p.W[4], tid, panbase + PMAT);
        build_panel_one<BF>(p.W[6], tid, panbase + 2 * PMAT);
        __threadfence();
    }
    preproc_core<BF>(p, pre, b, tid);

    int j = tid;
    float wr0[33], wz0[33], wn0[33];
#pragma unroll
    for (int d = 0; d < 33; ++d) {
        wr0[d] = ldw<BF>(p.W[0], (size_t)j * 33 + d);
        wz0[d] = ldw<BF>(p.W[0], ((size_t)j + 512) * 33 + d);
        wn0[d] = ldw<BF>(p.W[0], ((size_t)j + 1024) * 33 + d);
    }
    float bi0r = ldw<BF>(p.W[1], j), bi0z = ldw<BF>(p.W[1], j + 512), bi0n = ldw<BF>(p.W[1], j + 1024);
    float bh0r = ldw<BF>(p.W[3], j), bh0z = ldw<BF>(p.W[3], j + 512), bh0n = ldw<BF>(p.W[3], j + 1024);
    float bi1r = ldw<BF>(p.W[5], j), bi1z = ldw<BF>(p.W[5], j + 512), bi1n = ldw<BF>(p.W[5], j + 1024);
    float bh1r = ldw<BF>(p.W[7], j), bh1z = ldw<BF>(p.W[7], j + 512), bh1n = ldw<BF>(p.W[7], j + 1024);

    const void* pan0  = (const void*)panbase;
    const void* pan1x = (const void*)(panbase + PMAT);
    const void* pan1h = (const void*)(panbase + 2 * PMAT);
    const void *w0r = rowp<BF>(p.W[2], j), *w0z = rowp<BF>(p.W[2], j + 512), *w0n = rowp<BF>(p.W[2], j + 1024);
    const void *x1r = rowp<BF>(p.W[4], j), *x1z = rowp<BF>(p.W[4], j + 512), *x1n = rowp<BF>(p.W[4], j + 1024);
    const void *w1r = rowp<BF>(p.W[6], j), *w1z = rowp<BF>(p.W[6], j + 512), *w1n = rowp<BF>(p.W[6], j + 1024);

    h0[j] = 0.f; h1[j] = 0.f;
    float cacc = 0.f;
    __syncthreads();

    for (int tt = 0; tt < 512; ++tt) {
        if (j < 16) {
            float ang = TWO_PI * pre.ps2[tt] * (float)(j + 1);
            float sv, cv; sincosf(ang, &sv, &cv);
            eL[j] = cv; eL[16 + j] = sv;
        }
        if (j == 32) eL[32] = pre.ms2[tt];
        __syncthreads();
        float xr = bi0r, xz = bi0z, xn = bi0n;
#pragma unroll
        for (int d = 0; d < 33; ++d) {
            float e = eL[d];
            xr += wr0[d] * e; xz += wz0[d] * e; xn += wn0[d] * e;
        }
        float ar = bh0r, az = bh0z, an = bh0n;
        if constexpr (PAN) tridot_panel<BF>(pan0, j, h0, ar, az, an);
        else {
            for (int k = 0; k < 512; ++k) {
                float h = h0[k];
                ar += ldw<BF>(w0r, k) * h; az += ldw<BF>(w0z, k) * h; an += ldw<BF>(w0n, k) * h;
            }
        }
        float h0prev = h0[j];
        float r0 = 1.0f / (1.0f + expf(-(xr + ar)));
        float z0 = 1.0f / (1.0f + expf(-(xz + az)));
        float n0 = tanhf(xn + r0 * an);
        float nh0 = (1.0f - z0) * n0 + z0 * h0prev;
        __syncthreads();
        h0[j] = nh0;
        __syncthreads();
        float yr = bi1r, yz = bi1z, yn = bi1n;
        float cr = bh1r, cz = bh1z, cn = bh1n;
        if constexpr (PAN) {
            tridot_panel<BF>(pan1x, j, h0, yr, yz, yn);
            tridot_panel<BF>(pan1h, j, h1, cr, cz, cn);
        } else {
            for (int k = 0; k < 512; ++k) {
                float h = h0[k], g = h1[k];
                yr += ldw<BF>(x1r, k) * h; yz += ldw<BF>(x1z, k) * h; yn += ldw<BF>(x1n, k) * h;
                cr += ldw<BF>(w1r, k) * g; cz += ldw<BF>(w1z, k) * g; cn += ldw<BF>(w1n, k) * g;
            }
        }
        float h1prev = h1[j];
        float r1 = 1.0f / (1.0f + expf(-(yr + cr)));
        float z1 = 1.0f / (1.0f + expf(-(yz + cz)));
        float n1 = tanhf(yn + r1 * cn);
        float nh1 = (1.0f - z1) * n1 + z1 * h1prev;
        cacc += pre.vs2[tt] * nh1;
        __syncthreads();
        h1[j] = nh1;
    }
    __syncthreads();

    h0[j] = cacc / pre.nv;
    __syncthreads();
    float a1 = ldw<BF>(p.W[9], j) + dot512<BF>(rowp<BF>(p.W[8], j), h0);
    float g = 0.5f * a1 * (1.0f + erff(a1 * 0.70710678118654752440f));
    __syncthreads();
    h1[j] = g;
    __syncthreads();
    if (j < 16) {
        float a2 = ldw<BF>(p.W[11], j) + dot512<BF>(rowp<BF>(p.W[10], j), h1);
        if constexpr (BF) ((u16*)p.out)[(size_t)b * 16 + j] = f2b(a2);
        else              ((float*)p.out)[(size_t)b * 16 + j] = a2;
    }
}

__global__ __launch_bounds__(512) void fused_kernel_old(P p) {
    __shared__ ShmU S;
    bool bf = inputs_are_bf16(p.freq);
    u64 PMAT = bf ? 1572864ull : 3145728ull;
    bool pan = (p.ws && p.ws_size >= (u64)FLAGS_BYTES + 3 * PMAT);
    if (bf) { if (pan) run_all<true, true>(p, S);  else run_all<true, false>(p, S); }
    else    { if (pan) run_all<false, true>(p, S); else run_all<false, false>(p, S); }
}

// ======================= NEW: 6-piece pipeline, 192 active blocks =======================

template<bool BF>
__device__ void runA(const P& p, ShmU& S, int g, int hf, int tid, char* pan,
                     float* h0r, float* pp, int* flags) {
    build_piece<BF>(p.W[2], hf, tid, pan);
    __threadfence();
    int myb = 2 * g + hf, ob = 2 * g + (1 - hf);
    preproc_core<BF>(p, S.u.a.pre, myb, tid);
    sc_store_f(&pp[(size_t)myb * 2048 + tid], S.u.a.pre.ps2[tid]);
    sc_store_f(&pp[(size_t)myb * 2048 + 512 + tid], S.u.a.pre.ms2[tid]);
    sc_store_f(&pp[(size_t)myb * 2048 + 1024 + tid], S.u.a.pre.vs2[tid]);
    if (tid == 0) sc_store_f(&pp[(size_t)myb * 2048 + 1536], S.u.a.pre.nv);
    asm volatile("s_waitcnt vmcnt(0)" ::: "memory");
    __syncthreads();
    if (tid == 0) sc_store_i(&flags[FL(g, F_PRE + hf)], 1);
    S.u.a.psb[hf][tid] = S.u.a.pre.ps2[tid];
    S.u.a.msb[hf][tid] = S.u.a.pre.ms2[tid];
    if (tid == 0) waitge(&flags[FL(g, F_PRE + (1 - hf))], 1, &S.dead);
    __syncthreads();
    S.u.a.psb[1 - hf][tid] = sc_load_f(&pp[(size_t)ob * 2048 + tid]);
    S.u.a.msb[1 - hf][tid] = sc_load_f(&pp[(size_t)ob * 2048 + 512 + tid]);

    const int r = tid & 255, bb = tid >> 8;
    const int j = hf * 256 + r;
    float wr0[33], wz0[33], wn0[33];
#pragma unroll
    for (int d = 0; d < 33; ++d) {
        wr0[d] = ldw<BF>(p.W[0], (size_t)j * 33 + d);
        wz0[d] = ldw<BF>(p.W[0], ((size_t)j + 512) * 33 + d);
        wn0[d] = ldw<BF>(p.W[0], ((size_t)j + 1024) * 33 + d);
    }
    float bi0r = ldw<BF>(p.W[1], j), bi0z = ldw<BF>(p.W[1], j + 512), bi0n = ldw<BF>(p.W[1], j + 1024);
    float bh0r = ldw<BF>(p.W[3], j), bh0z = ldw<BF>(p.W[3], j + 512), bh0n = ldw<BF>(p.W[3], j + 1024);

    S.u.a.h0L[tid] = 0.f; S.u.a.h0L[tid + 512] = 0.f;
    __syncthreads();

    for (int t = 0; t < 512; ++t) {
        if (t > 0) {
            if (tid == 0) waitge(&flags[FL(g, F_A + (1 - hf))], t, &S.dead);
            __syncthreads();
            S.u.a.h0L[bb * 512 + (1 - hf) * 256 + r] =
                sc_load_f(&h0r[(size_t)g * 2048 + ((t - 1) & 1) * 1024 + (1 - hf) * 512 + bb * 256 + r]);
            __syncthreads();
            if (tid == 0) sc_store_i(&flags[FL(g, G_A + hf)], t);
        }
        if (tid < 16) {
            float ang = TWO_PI * S.u.a.psb[0][t] * (float)(tid + 1);
            float sv, cv; sincosf(ang, &sv, &cv);
            S.u.a.eL[0][tid] = cv; S.u.a.eL[0][16 + tid] = sv;
        } else if (tid < 32) {
            int k = tid - 16;
            float ang = TWO_PI * S.u.a.psb[1][t] * (float)(k + 1);
            float sv, cv; sincosf(ang, &sv, &cv);
            S.u.a.eL[1][k] = cv; S.u.a.eL[1][16 + k] = sv;
        }
        if (tid == 32) S.u.a.eL[0][32] = S.u.a.msb[0][t];
        if (tid == 33) S.u.a.eL[1][32] = S.u.a.msb[1][t];
        __syncthreads();
        float xr = bi0r, xz = bi0z, xn = bi0n;
#pragma unroll
        for (int d = 0; d < 33; ++d) {
            float e = S.u.a.eL[bb][d];
            xr += wr0[d] * e; xz += wz0[d] * e; xn += wn0[d] * e;
        }
        float ar = bh0r, az = bh0z, an = bh0n;
        tridot_piece<BF>(pan, r, &S.u.a.h0L[bb * 512], ar, az, an);
        float h0prev = S.u.a.h0L[bb * 512 + j];
        float r0 = 1.0f / (1.0f + expf(-(xr + ar)));
        float z0 = 1.0f / (1.0f + expf(-(xz + az)));
        float n0 = tanhf(xn + r0 * an);
        float nh0 = (1.0f - z0) * n0 + z0 * h0prev;
        __syncthreads();                          // h0L(t-1) reads done
        S.u.a.h0L[bb * 512 + j] = nh0;
        if (tid == 0 && t >= 2) {                 // WAR: slot t&1 consumers done with t-2
            waitge(&flags[FL(g, G_A + (1 - hf))], t - 1, &S.dead);
            waitge(&flags[FL(g, G_B + 0)], t - 1, &S.dead);
            waitge(&flags[FL(g, G_B + 1)], t - 1, &S.dead);
        }
        __syncthreads();
        sc_store_f(&h0r[(size_t)g * 2048 + (t & 1) * 1024 + hf * 512 + bb * 256 + r], nh0);
        asm volatile("s_waitcnt vmcnt(0)" ::: "memory");
        __syncthreads();
        if (tid == 0) sc_store_i(&flags[FL(g, F_A + hf)], t + 1);
    }
}

template<bool BF>
__device__ void runB(const P& p, ShmU& S, int g, int hf, int tid, char* pan,
                     float* h0r, float* yrng, int* flags) {
    build_piece<BF>(p.W[4], hf, tid, pan);
    __threadfence();
    __syncthreads();
    const int r = tid & 255, bb = tid >> 8;
    const int j = hf * 256 + r;
    float bi1r = ldw<BF>(p.W[5], j), bi1z = ldw<BF>(p.W[5], j + 512), bi1n = ldw<BF>(p.W[5], j + 1024);

    for (int t = 0; t < 512; ++t) {
        if (tid == 0) {
            waitge(&flags[FL(g, F_A + 0)], t + 1, &S.dead);
            waitge(&flags[FL(g, F_A + 1)], t + 1, &S.dead);
        }
        __syncthreads();
        S.u.b.h0loc[bb * 512 + r] =
            sc_load_f(&h0r[(size_t)g * 2048 + (t & 1) * 1024 + 0 * 512 + bb * 256 + r]);
        S.u.b.h0loc[bb * 512 + 256 + r] =
            sc_load_f(&h0r[(size_t)g * 2048 + (t & 1) * 1024 + 1 * 512 + bb * 256 + r]);
        __syncthreads();
        if (tid == 0) sc_store_i(&flags[FL(g, G_B + hf)], t + 1);
        float yr = bi1r, yz = bi1z, yn = bi1n;
        tridot_piece<BF>(pan, r, &S.u.b.h0loc[bb * 512], yr, yz, yn);
        if (tid == 0 && t >= 2) waitge(&flags[FL(g, G_C + hf)], t - 1, &S.dead);
        __syncthreads();
        float* slot = &yrng[(size_t)g * 6144 + (t & 1) * 3072 + hf * 1536];
        sc_store_f(&slot[bb * 256 + r], yr);
        sc_store_f(&slot[512 + bb * 256 + r], yz);
        sc_store_f(&slot[1024 + bb * 256 + r], yn);
        asm volatile("s_waitcnt vmcnt(0)" ::: "memory");
        __syncthreads();
        if (tid == 0) sc_store_i(&flags[FL(g, F_B + hf)], t + 1);
    }
}

template<bool BF>
__device__ void runC(const P& p, ShmU& S, int g, int hf, int tid, char* pan,
                     float* yrng, float* h1r, float* pp, float* ctxb, int* flags) {
    build_piece<BF>(p.W[6], hf, tid, pan);
    __threadfence();
    if (tid == 0) {
        waitge(&flags[FL(g, F_PRE + 0)], 1, &S.dead);
        waitge(&flags[FL(g, F_PRE + 1)], 1, &S.dead);
    }
    __syncthreads();
    S.u.c.vs2L[0][tid] = sc_load_f(&pp[(size_t)(2 * g) * 2048 + 1024 + tid]);
    S.u.c.vs2L[1][tid] = sc_load_f(&pp[(size_t)(2 * g + 1) * 2048 + 1024 + tid]);
    if (tid == 0) {
        S.u.c.nvL[0] = sc_load_f(&pp[(size_t)(2 * g) * 2048 + 1536]);
        S.u.c.nvL[1] = sc_load_f(&pp[(size_t)(2 * g + 1) * 2048 + 1536]);
    }
    S.u.c.h1L[tid] = 0.f; S.u.c.h1L[tid + 512] = 0.f;
    __syncthreads();

    const int r = tid & 255, bb = tid >> 8;
    const int j = hf * 256 + r;
    float bh1r = ldw<BF>(p.W[7], j), bh1z = ldw<BF>(p.W[7], j + 512), bh1n = ldw<BF>(p.W[7], j + 1024);
    float cacc = 0.f;

    for (int t = 0; t < 512; ++t) {
        if (tid == 0) {
            waitge(&flags[FL(g, F_B + hf)], t + 1, &S.dead);
            if (t > 0) waitge(&flags[FL(g, F_C + (1 - hf))], t, &S.dead);
        }
        __syncthreads();
        if (t > 0) {
            S.u.c.h1L[bb * 512 + (1 - hf) * 256 + r] =
                sc_load_f(&h1r[(size_t)g * 2048 + ((t - 1) & 1) * 1024 + (1 - hf) * 512 + bb * 256 + r]);
        }
        const float* slot = &yrng[(size_t)g * 6144 + (t & 1) * 3072 + hf * 1536];
        float yr = sc_load_f(&slot[bb * 256 + r]);
        float yz = sc_load_f(&slot[512 + bb * 256 + r]);
        float yn = sc_load_f(&slot[1024 + bb * 256 + r]);
        __syncthreads();
        if (tid == 0) sc_store_i(&flags[FL(g, G_C + hf)], t + 1);
        float cr = bh1r, cz = bh1z, cn = bh1n;
        tridot_piece<BF>(pan, r, &S.u.c.h1L[bb * 512], cr, cz, cn);
        float h1prev = S.u.c.h1L[bb * 512 + j];
        float r1 = 1.0f / (1.0f + expf(-(yr + cr)));
        float z1 = 1.0f / (1.0f + expf(-(yz + cz)));
        float n1 = tanhf(yn + r1 * cn);
        float nh1 = (1.0f - z1) * n1 + z1 * h1prev;
        cacc += S.u.c.vs2L[bb][t] * nh1;
        __syncthreads();                          // h1L(t-1) reads done
        S.u.c.h1L[bb * 512 + j] = nh1;
        if (tid == 0 && t >= 2) waitge(&flags[FL(g, G_C + (1 - hf))], t - 1, &S.dead);
        __syncthreads();
        sc_store_f(&h1r[(size_t)g * 2048 + (t & 1) * 1024 + hf * 512 + bb * 256 + r], nh1);
        asm volatile("s_waitcnt vmcnt(0)" ::: "memory");
        __syncthreads();
        if (tid == 0) sc_store_i(&flags[FL(g, F_C + hf)], t + 1);
    }

    // ---- ctx exchange + head (C_hf handles batch 2g+hf) ----
    sc_store_f(&ctxb[(size_t)g * 1024 + hf * 512 + bb * 256 + r], cacc);
    asm volatile("s_waitcnt vmcnt(0)" ::: "memory");
    __syncthreads();
    if (tid == 0) {
        sc_store_i(&flags[FL(g, F_CTX + hf)], 1);
        waitge(&flags[FL(g, F_CTX + (1 - hf))], 1, &S.dead);
    }
    __syncthreads();
    float nv = S.u.c.nvL[hf];
    S.u.c.ctxL[tid] = sc_load_f(&ctxb[(size_t)g * 1024 + (tid >> 8) * 512 + hf * 256 + (tid & 255)]) / nv;
    __syncthreads();
    float a1 = ldw<BF>(p.W[9], tid) + dot512<BF>(rowp<BF>(p.W[8], tid), S.u.c.ctxL);
    float gg = 0.5f * a1 * (1.0f + erff(a1 * 0.70710678118654752440f));
    __syncthreads();
    S.u.c.gL[tid] = gg;
    __syncthreads();
    if (tid < 16) {
        float a2 = ldw<BF>(p.W[11], tid) + dot512<BF>(rowp<BF>(p.W[10], tid), S.u.c.gL);
        int hb = 2 * g + hf;
        if constexpr (BF) ((u16*)p.out)[(size_t)hb * 16 + tid] = f2b(a2);
        else              ((float*)p.out)[(size_t)hb * 16 + tid] = a2;
    }
}

template<bool BF>
__device__ void run_pipe(const P& p, ShmU& S) {
    const int bid = blockIdx.x;
    const int piece = bid & 7;                   // bid%8 -> XCD (empirical): cluster pieces
    if (piece >= 6) return;
    const int g = bid >> 3;                      // 0..31
    const int role = piece >> 1, hf = piece & 1;
    const int tid = threadIdx.x;
    if (tid == 0) S.dead = 0;
    __syncthreads();

    char* wsb = (char*)p.ws;
    int* flags = (int*)wsb;
    const size_t PIECE = BF ? 786432 : 1572864;
    char* pans = wsb + FLAGS_BYTES;
    char* mypan = pans + (size_t)piece * PIECE;
    float* h0r  = (float*)(pans + 6 * PIECE);                // [32][2][2][2][256]
    float* yrng = h0r + (size_t)32 * 2048;                   // [32][2][2][3][2][256]
    float* h1r  = yrng + (size_t)32 * 6144;                  // [32][2][2][2][256]
    float* pp   = h1r + (size_t)32 * 2048;                   // [64][2048]
    float* ctxb = pp + (size_t)64 * 2048;                    // [32][2][2][256]

    if (role == 0)      runA<BF>(p, S, g, hf, tid, mypan, h0r, pp, flags);
    else if (role == 1) runB<BF>(p, S, g, hf, tid, mypan, h0r, yrng, flags);
    else                runC<BF>(p, S, g, hf, tid, mypan, yrng, h1r, pp, ctxb, flags);
}

__global__ __launch_bounds__(512) void fused_kernel_pipe(P p) {
    __shared__ ShmU S;
    if (inputs_are_bf16(p.freq)) run_pipe<true>(p, S);
    else                         run_pipe<false>(p, S);
}

extern "C" void kernel_launch(void* const* d_in, const int* in_sizes, int n_in,
                              void* d_out, int out_size, void* d_ws, size_t ws_size,
                              hipStream_t stream) {
    P p;
    p.lc = d_in[0];
    p.freq = d_in[2];
    for (int i = 0; i < 12; ++i) p.W[i] = d_in[3 + i];
    p.out = d_out;
    p.ws = d_ws;
    p.ws_size = (unsigned long long)ws_size;

    // f32 sizing (worst case): 32768 + 6*1572864 + 262144 + 786432 + 262144
    //                          + 524288 + 131072 = 11,436,032 B
    const size_t need_pipe = 11436032ull;
    if (d_ws && ws_size >= need_pipe) {
        hipMemsetAsync(d_ws, 0, FLAGS_BYTES, stream);
        fused_kernel_pipe<<<256, 512, 0, stream>>>(p);
    } else {
        fused_kernel_old<<<64, 512, 0, stream>>>(p);
    }
    (void)in_sizes; (void)n_in; (void)out_size;
}